// Round 2
// baseline (800.331 us; speedup 1.0000x reference)
//
#include <hip/hip_runtime.h>
#include <math.h>

#define NN 100000
#define NE 1600000
#define FIN 64
#define HID 16
#define NC 40

// deg[d] += ew ; cnt[d] += 1   (fused histogram)
__global__ void k_deg_hist(const int* __restrict__ dst, const float* __restrict__ ew,
                           float* __restrict__ deg, int* __restrict__ cnt) {
    int e = blockIdx.x * blockDim.x + threadIdx.x;
    if (e < NE) {
        int d = dst[e];
        atomicAdd(&deg[d], ew[e]);
        atomicAdd(&cnt[d], 1);
    }
}

__global__ void k_dinv(float* deg) {
    int i = blockIdx.x * blockDim.x + threadIdx.x;
    if (i < NN) {
        float d = deg[i];
        deg[i] = d > 0.f ? rsqrtf(fmaxf(d, 1e-30f)) : 0.f;
    }
}

// single-workgroup exclusive scan of cnt[0..NN) -> row_ptr, cursor (both = row start)
__global__ void __launch_bounds__(1024) k_scan(const int* __restrict__ cnt,
                                               int* __restrict__ row_ptr,
                                               int* __restrict__ cursor) {
    __shared__ int sums[1024];
    const int T = 1024;
    int tid = threadIdx.x;
    const int CH = (NN + T - 1) / T;  // 98
    int base = tid * CH;
    int s = 0;
    for (int i = 0; i < CH; ++i) {
        int idx = base + i;
        if (idx < NN) s += cnt[idx];
    }
    sums[tid] = s;
    __syncthreads();
    // Hillis-Steele inclusive scan
    for (int off = 1; off < T; off <<= 1) {
        int v = (tid >= off) ? sums[tid - off] : 0;
        __syncthreads();
        sums[tid] += v;
        __syncthreads();
    }
    int running = sums[tid] - s;  // exclusive
    for (int i = 0; i < CH; ++i) {
        int idx = base + i;
        if (idx < NN) {
            row_ptr[idx] = running;
            cursor[idx] = running;
            running += cnt[idx];
        }
    }
    if (tid == T - 1) row_ptr[NN] = running;
}

// place edges into CSR rows; fuses norm computation
__global__ void k_place(const int* __restrict__ src, const int* __restrict__ dst,
                        const float* __restrict__ ew, const float* __restrict__ dinv,
                        int* __restrict__ cursor,
                        int* __restrict__ src_sorted, float* __restrict__ norm_sorted) {
    int e = blockIdx.x * blockDim.x + threadIdx.x;
    if (e >= NE) return;
    int d = dst[e];
    int s = src[e];
    int p = atomicAdd(&cursor[d], 1);
    src_sorted[p] = s;
    norm_sorted[p] = -dinv[s] * ew[e] * dinv[d];
}

// A1[n][j] = x[n]@W1[0][:,j];  B0[n][j] = x[n]@W1[1][:,j]
__global__ void k_mm1(const float* __restrict__ x, const float* __restrict__ W1,
                      float* __restrict__ A1, float* __restrict__ B0) {
    __shared__ float w[2 * FIN * HID];
    int tid = threadIdx.x;
    for (int i = tid; i < 2 * FIN * HID; i += 256) w[i] = W1[i];
    __syncthreads();
    int node = blockIdx.x * 8 + (tid >> 5);
    int c = tid & 31;
    int sel = c >> 4, jj = c & 15;
    if (node >= NN) return;
    const float* xr = x + node * FIN;
    const float* wp = w + sel * (FIN * HID) + jj;
    float acc = 0.f;
    #pragma unroll
    for (int f = 0; f < FIN; ++f) acc += xr[f] * wp[f * HID];
    if (sel == 0) A1[node * HID + jj] = acc;
    else          B0[node * HID + jj] = acc;
}

// per-node gather over incoming edges + relu(A1 + acc + b1) -> h
__global__ void k_gather16(const int* __restrict__ row_ptr, const int* __restrict__ src_sorted,
                           const float* __restrict__ norm_sorted, const float* __restrict__ B0,
                           const float* __restrict__ A1, const float* __restrict__ b1,
                           float* __restrict__ h) {
    int node = blockIdx.x * 16 + (threadIdx.x >> 4);
    int j = threadIdx.x & 15;
    if (node >= NN) return;
    int beg = row_ptr[node], end = row_ptr[node + 1];
    float acc = 0.f;
    for (int p = beg; p < end; ++p) {
        int s = src_sorted[p];
        float w = norm_sorted[p];
        acc += w * B0[s * HID + j];
    }
    float v = A1[node * HID + j] + acc + b1[j];
    h[node * HID + j] = v > 0.f ? v : 0.f;
}

// Aout[n][j] = h[n]@W2[0][:,j] + b2[j];  B1[n][j] = h[n]@W2[1][:,j]
__global__ void k_mm2(const float* __restrict__ h, const float* __restrict__ W2,
                      const float* __restrict__ b2,
                      float* __restrict__ Aout, float* __restrict__ B1) {
    __shared__ float w[2 * HID * NC];
    int tid = threadIdx.x;
    for (int i = tid; i < 2 * HID * NC; i += 320) w[i] = W2[i];
    __syncthreads();
    int node = blockIdx.x * 4 + tid / 80;
    int c = tid % 80;
    int sel = c / 40, jj = c - sel * 40;
    if (node >= NN) return;
    const float* hr = h + node * HID;
    const float* wp = w + sel * (HID * NC) + jj;
    float acc = 0.f;
    #pragma unroll
    for (int f = 0; f < HID; ++f) acc += hr[f] * wp[f * NC];
    if (sel == 0) Aout[node * NC + jj] = acc + b2[jj];
    else          B1[node * NC + jj] = acc;
}

// wave per node: gather layer-2 edges, add Aout, fused log_softmax, single store
__global__ void k_gather40_lsm(const int* __restrict__ row_ptr, const int* __restrict__ src_sorted,
                               const float* __restrict__ norm_sorted, const float* __restrict__ B1,
                               const float* __restrict__ Aout, float* __restrict__ out) {
    int node = blockIdx.x * 4 + (threadIdx.x >> 6);
    int lane = threadIdx.x & 63;
    if (node >= NN) return;
    int beg = row_ptr[node], end = row_ptr[node + 1];
    float acc = 0.f;
    for (int p = beg; p < end; ++p) {
        int s = src_sorted[p];
        float w = norm_sorted[p];
        if (lane < NC) acc += w * B1[s * NC + lane];
    }
    float v = (lane < NC) ? Aout[node * NC + lane] + acc : -INFINITY;
    float m = v;
    #pragma unroll
    for (int s = 32; s > 0; s >>= 1) m = fmaxf(m, __shfl_xor(m, s, 64));
    float ex = (lane < NC) ? expf(v - m) : 0.f;
    float sum = ex;
    #pragma unroll
    for (int s = 32; s > 0; s >>= 1) sum += __shfl_xor(sum, s, 64);
    if (lane < NC) out[node * NC + lane] = v - m - logf(sum);
}

extern "C" void kernel_launch(void* const* d_in, const int* in_sizes, int n_in,
                              void* d_out, int out_size, void* d_ws, size_t ws_size,
                              hipStream_t stream) {
    const float* x  = (const float*)d_in[0];
    const float* ew = (const float*)d_in[1];
    const float* W1 = (const float*)d_in[2];
    const float* b1 = (const float*)d_in[3];
    const float* W2 = (const float*)d_in[4];
    const float* b2 = (const float*)d_in[5];
    const int*   ei = (const int*)d_in[6];
    const int* src = ei;
    const int* dst = ei + NE;
    float* out = (float*)d_out;

    const int NPAD = 100352;  // NN rounded up, keeps 128B alignment
    float* ws          = (float*)d_ws;
    float* deg         = ws;                         // NPAD f
    int*   cnt         = (int*)(deg + NPAD);         // NPAD i
    int*   row_ptr     = cnt + NPAD;                 // NPAD i (uses NN+1)
    int*   cursor      = row_ptr + NPAD;             // NPAD i
    int*   src_sorted  = cursor + NPAD;              // NE i
    float* norm_sorted = (float*)(src_sorted + NE);  // NE f
    float* A1          = norm_sorted + NE;           // NN*HID f
    float* B0          = A1 + NN * HID;              // NN*HID f
    float* h           = B0 + NN * HID;              // NN*HID f
    float* Aout        = h + NN * HID;               // NN*NC f
    float* B1          = Aout + NN * NC;             // NN*NC f
    // total ~66 MB

    hipMemsetAsync(deg, 0, NPAD * sizeof(float), stream);
    hipMemsetAsync(cnt, 0, NPAD * sizeof(int), stream);

    k_deg_hist<<<(NE + 255) / 256, 256, 0, stream>>>(dst, ew, deg, cnt);
    k_dinv<<<(NN + 255) / 256, 256, 0, stream>>>(deg);
    k_scan<<<1, 1024, 0, stream>>>(cnt, row_ptr, cursor);
    k_place<<<(NE + 255) / 256, 256, 0, stream>>>(src, dst, ew, deg, cursor,
                                                  src_sorted, norm_sorted);
    k_mm1<<<(NN + 7) / 8, 256, 0, stream>>>(x, W1, A1, B0);
    k_gather16<<<(NN + 15) / 16, 256, 0, stream>>>(row_ptr, src_sorted, norm_sorted,
                                                   B0, A1, b1, h);
    k_mm2<<<(NN + 3) / 4, 320, 0, stream>>>(h, W2, b2, Aout, B1);
    k_gather40_lsm<<<(NN + 3) / 4, 256, 0, stream>>>(row_ptr, src_sorted, norm_sorted,
                                                     B1, Aout, out);
}

// Round 3
// 530.042 us; speedup vs baseline: 1.5099x; 1.5099x over previous
//
#include <hip/hip_runtime.h>
#include <math.h>

#define NN 100000
#define NE 1600000
#define FIN 64
#define HID 16
#define NC 40

#define SCAN_CHUNK 1024
#define NBLK ((NN + SCAN_CHUNK - 1) / SCAN_CHUNK)  // 98

// deg[d] += ew ; cnt[d] += 1   (fused histogram)
__global__ void k_deg_hist(const int* __restrict__ dst, const float* __restrict__ ew,
                           float* __restrict__ deg, int* __restrict__ cnt) {
    int e = blockIdx.x * blockDim.x + threadIdx.x;
    if (e < NE) {
        int d = dst[e];
        atomicAdd(&deg[d], ew[e]);
        atomicAdd(&cnt[d], 1);
    }
}

__global__ void k_dinv(float* deg) {
    int i = blockIdx.x * blockDim.x + threadIdx.x;
    if (i < NN) {
        float d = deg[i];
        deg[i] = d > 0.f ? rsqrtf(fmaxf(d, 1e-30f)) : 0.f;
    }
}

// phase 1: per-block sum of a 1024-int chunk of cnt
__global__ void k_scan1(const int* __restrict__ cnt, int* __restrict__ bsum) {
    __shared__ int red[4];
    int b = blockIdx.x, tid = threadIdx.x;
    int idx = b * SCAN_CHUNK + tid * 4;
    int s = 0;
    if (idx < NN) {  // NN % 4 == 0 so int4 stays in bounds
        int4 v = *(const int4*)&cnt[idx];
        s = v.x + v.y + v.z + v.w;
    }
    #pragma unroll
    for (int off = 32; off > 0; off >>= 1) s += __shfl_down(s, off, 64);
    if ((tid & 63) == 0) red[tid >> 6] = s;
    __syncthreads();
    if (tid == 0) bsum[b] = red[0] + red[1] + red[2] + red[3];
}

// phase 2: exclusive scan of the 98 block sums (one tiny block)
__global__ void k_scan2(const int* __restrict__ bsum, int* __restrict__ boff,
                        int* __restrict__ row_ptr) {
    __shared__ int sh[128];
    int tid = threadIdx.x;
    int v = tid < NBLK ? bsum[tid] : 0;
    sh[tid] = v;
    __syncthreads();
    #pragma unroll
    for (int off = 1; off < 128; off <<= 1) {
        int t = tid >= off ? sh[tid - off] : 0;
        __syncthreads();
        sh[tid] += t;
        __syncthreads();
    }
    if (tid < NBLK) boff[tid] = sh[tid] - v;
    if (tid == 0) row_ptr[NN] = NE;  // every edge is placed
}

// phase 3: block-local exclusive scan + block offset -> row_ptr, cursor
__global__ void k_scan3(const int* __restrict__ cnt, const int* __restrict__ boff,
                        int* __restrict__ row_ptr, int* __restrict__ cursor) {
    __shared__ int sh[256];
    int b = blockIdx.x, tid = threadIdx.x;
    int idx = b * SCAN_CHUNK + tid * 4;
    int4 v = {0, 0, 0, 0};
    if (idx < NN) v = *(const int4*)&cnt[idx];
    int s = v.x + v.y + v.z + v.w;
    sh[tid] = s;
    __syncthreads();
    #pragma unroll
    for (int off = 1; off < 256; off <<= 1) {
        int t = tid >= off ? sh[tid - off] : 0;
        __syncthreads();
        sh[tid] += t;
        __syncthreads();
    }
    if (idx < NN) {
        int r0 = sh[tid] - s + boff[b];
        int4 r;
        r.x = r0; r.y = r0 + v.x; r.z = r.y + v.y; r.w = r.z + v.z;
        *(int4*)&row_ptr[idx] = r;
        *(int4*)&cursor[idx] = r;
    }
}

// place edges into CSR rows; fuses norm computation; packed (src, norm) 8B record
__global__ void k_place(const int* __restrict__ src, const int* __restrict__ dst,
                        const float* __restrict__ ew, const float* __restrict__ dinv,
                        int* __restrict__ cursor, int2* __restrict__ edges) {
    int e = blockIdx.x * blockDim.x + threadIdx.x;
    if (e >= NE) return;
    int d = dst[e];
    int s = src[e];
    int p = atomicAdd(&cursor[d], 1);
    float w = -dinv[s] * ew[e] * dinv[d];
    edges[p] = make_int2(s, __float_as_int(w));
}

// A1[n][j] = x[n]@W1[0][:,j];  B0[n][j] = x[n]@W1[1][:,j]
__global__ void k_mm1(const float* __restrict__ x, const float* __restrict__ W1,
                      float* __restrict__ A1, float* __restrict__ B0) {
    __shared__ float w[2 * FIN * HID];
    int tid = threadIdx.x;
    for (int i = tid; i < 2 * FIN * HID; i += 256) w[i] = W1[i];
    __syncthreads();
    int node = blockIdx.x * 8 + (tid >> 5);
    int c = tid & 31;
    int sel = c >> 4, jj = c & 15;
    if (node >= NN) return;
    const float* xr = x + node * FIN;
    const float* wp = w + sel * (FIN * HID) + jj;
    float acc = 0.f;
    #pragma unroll
    for (int f = 0; f < FIN; ++f) acc += xr[f] * wp[f * HID];
    if (sel == 0) A1[node * HID + jj] = acc;
    else          B0[node * HID + jj] = acc;
}

// per-node gather over incoming edges + relu(A1 + acc + b1) -> h
__global__ void k_gather16(const int* __restrict__ row_ptr, const int2* __restrict__ edges,
                           const float* __restrict__ B0,
                           const float* __restrict__ A1, const float* __restrict__ b1,
                           float* __restrict__ h) {
    int node = blockIdx.x * 16 + (threadIdx.x >> 4);
    int j = threadIdx.x & 15;
    if (node >= NN) return;
    int beg = row_ptr[node], end = row_ptr[node + 1];
    float acc = 0.f;
    for (int p = beg; p < end; ++p) {
        int2 pk = edges[p];
        acc += __int_as_float(pk.y) * B0[pk.x * HID + j];
    }
    float v = A1[node * HID + j] + acc + b1[j];
    h[node * HID + j] = v > 0.f ? v : 0.f;
}

// Aout[n][j] = h[n]@W2[0][:,j] + b2[j];  B1[n][j] = h[n]@W2[1][:,j]
__global__ void k_mm2(const float* __restrict__ h, const float* __restrict__ W2,
                      const float* __restrict__ b2,
                      float* __restrict__ Aout, float* __restrict__ B1) {
    __shared__ float w[2 * HID * NC];
    int tid = threadIdx.x;
    for (int i = tid; i < 2 * HID * NC; i += 320) w[i] = W2[i];
    __syncthreads();
    int node = blockIdx.x * 4 + tid / 80;
    int c = tid % 80;
    int sel = c / 40, jj = c - sel * 40;
    if (node >= NN) return;
    const float* hr = h + node * HID;
    const float* wp = w + sel * (HID * NC) + jj;
    float acc = 0.f;
    #pragma unroll
    for (int f = 0; f < HID; ++f) acc += hr[f] * wp[f * NC];
    if (sel == 0) Aout[node * NC + jj] = acc + b2[jj];
    else          B1[node * NC + jj] = acc;
}

// wave per node: gather layer-2 edges, add Aout, fused log_softmax, single store
__global__ void k_gather40_lsm(const int* __restrict__ row_ptr, const int2* __restrict__ edges,
                               const float* __restrict__ B1,
                               const float* __restrict__ Aout, float* __restrict__ out) {
    int node = blockIdx.x * 4 + (threadIdx.x >> 6);
    int lane = threadIdx.x & 63;
    if (node >= NN) return;
    int beg = row_ptr[node], end = row_ptr[node + 1];
    float acc = 0.f;
    for (int p = beg; p < end; ++p) {
        int2 pk = edges[p];
        if (lane < NC) acc += __int_as_float(pk.y) * B1[pk.x * NC + lane];
    }
    float v = (lane < NC) ? Aout[node * NC + lane] + acc : -INFINITY;
    float m = v;
    #pragma unroll
    for (int s = 32; s > 0; s >>= 1) m = fmaxf(m, __shfl_xor(m, s, 64));
    float ex = (lane < NC) ? expf(v - m) : 0.f;
    float sum = ex;
    #pragma unroll
    for (int s = 32; s > 0; s >>= 1) sum += __shfl_xor(sum, s, 64);
    if (lane < NC) out[node * NC + lane] = v - m - logf(sum);
}

extern "C" void kernel_launch(void* const* d_in, const int* in_sizes, int n_in,
                              void* d_out, int out_size, void* d_ws, size_t ws_size,
                              hipStream_t stream) {
    const float* x  = (const float*)d_in[0];
    const float* ew = (const float*)d_in[1];
    const float* W1 = (const float*)d_in[2];
    const float* b1 = (const float*)d_in[3];
    const float* W2 = (const float*)d_in[4];
    const float* b2 = (const float*)d_in[5];
    const int*   ei = (const int*)d_in[6];
    const int* src = ei;
    const int* dst = ei + NE;
    float* out = (float*)d_out;

    const int NPAD = 100352;  // NN rounded up, keeps 16B alignment everywhere
    float* ws      = (float*)d_ws;
    float* deg     = ws;                       // NPAD f
    int*   cnt     = (int*)(deg + NPAD);       // NPAD i
    int*   row_ptr = cnt + NPAD;               // NPAD i (uses NN+1)
    int*   cursor  = row_ptr + NPAD;           // NPAD i
    int*   bsum    = cursor + NPAD;            // 128 i
    int*   boff    = bsum + 128;               // 128 i
    int2*  edges   = (int2*)(boff + 128);      // NE int2 (16B-aligned base)
    float* A1      = (float*)(edges + NE);     // NN*HID f
    float* B0      = A1 + NN * HID;            // NN*HID f
    float* h       = B0 + NN * HID;            // NN*HID f
    float* Aout    = h + NN * HID;             // NN*NC f
    float* B1      = Aout + NN * NC;           // NN*NC f

    hipMemsetAsync(deg, 0, NPAD * sizeof(float), stream);
    hipMemsetAsync(cnt, 0, NPAD * sizeof(int), stream);

    k_deg_hist<<<(NE + 255) / 256, 256, 0, stream>>>(dst, ew, deg, cnt);
    k_dinv<<<(NN + 255) / 256, 256, 0, stream>>>(deg);
    k_scan1<<<NBLK, 256, 0, stream>>>(cnt, bsum);
    k_scan2<<<1, 128, 0, stream>>>(bsum, boff, row_ptr);
    k_scan3<<<NBLK, 256, 0, stream>>>(cnt, boff, row_ptr, cursor);
    k_place<<<(NE + 255) / 256, 256, 0, stream>>>(src, dst, ew, deg, cursor, edges);
    k_mm1<<<(NN + 7) / 8, 256, 0, stream>>>(x, W1, A1, B0);
    k_gather16<<<(NN + 15) / 16, 256, 0, stream>>>(row_ptr, edges, B0, A1, b1, h);
    k_mm2<<<(NN + 3) / 4, 320, 0, stream>>>(h, W2, b2, Aout, B1);
    k_gather40_lsm<<<(NN + 3) / 4, 256, 0, stream>>>(row_ptr, edges, B1, Aout, out);
}

// Round 4
// 403.464 us; speedup vs baseline: 1.9837x; 1.3137x over previous
//
#include <hip/hip_runtime.h>
#include <math.h>

#define NN 100000
#define NE 1600000
#define FIN 64
#define HID 16
#define NC 40

#define SCAN_CHUNK 1024
#define NBLK ((NN + SCAN_CHUNK - 1) / SCAN_CHUNK)  // 98

// deg[d] += ew ; cnt[d] += 1   (fused histogram)
__global__ void k_deg_hist(const int* __restrict__ dst, const float* __restrict__ ew,
                           float* __restrict__ deg, int* __restrict__ cnt) {
    int e = blockIdx.x * blockDim.x + threadIdx.x;
    if (e < NE) {
        int d = dst[e];
        atomicAdd(&deg[d], ew[e]);
        atomicAdd(&cnt[d], 1);
    }
}

__global__ void k_dinv(float* deg) {
    int i = blockIdx.x * blockDim.x + threadIdx.x;
    if (i < NN) {
        float d = deg[i];
        deg[i] = d > 0.f ? rsqrtf(fmaxf(d, 1e-30f)) : 0.f;
    }
}

// phase 1: per-block sum of a 1024-int chunk of cnt
__global__ void k_scan1(const int* __restrict__ cnt, int* __restrict__ bsum) {
    __shared__ int red[4];
    int b = blockIdx.x, tid = threadIdx.x;
    int idx = b * SCAN_CHUNK + tid * 4;
    int s = 0;
    if (idx < NN) {
        int4 v = *(const int4*)&cnt[idx];
        s = v.x + v.y + v.z + v.w;
    }
    #pragma unroll
    for (int off = 32; off > 0; off >>= 1) s += __shfl_down(s, off, 64);
    if ((tid & 63) == 0) red[tid >> 6] = s;
    __syncthreads();
    if (tid == 0) bsum[b] = red[0] + red[1] + red[2] + red[3];
}

// phase 2: exclusive scan of the 98 block sums
__global__ void k_scan2(const int* __restrict__ bsum, int* __restrict__ boff,
                        int* __restrict__ row_ptr) {
    __shared__ int sh[128];
    int tid = threadIdx.x;
    int v = tid < NBLK ? bsum[tid] : 0;
    sh[tid] = v;
    __syncthreads();
    #pragma unroll
    for (int off = 1; off < 128; off <<= 1) {
        int t = tid >= off ? sh[tid - off] : 0;
        __syncthreads();
        sh[tid] += t;
        __syncthreads();
    }
    if (tid < NBLK) boff[tid] = sh[tid] - v;
    if (tid == 0) row_ptr[NN] = NE;
}

// phase 3: block-local exclusive scan + block offset -> row_ptr, cursor
__global__ void k_scan3(const int* __restrict__ cnt, const int* __restrict__ boff,
                        int* __restrict__ row_ptr, int* __restrict__ cursor) {
    __shared__ int sh[256];
    int b = blockIdx.x, tid = threadIdx.x;
    int idx = b * SCAN_CHUNK + tid * 4;
    int4 v = {0, 0, 0, 0};
    if (idx < NN) v = *(const int4*)&cnt[idx];
    int s = v.x + v.y + v.z + v.w;
    sh[tid] = s;
    __syncthreads();
    #pragma unroll
    for (int off = 1; off < 256; off <<= 1) {
        int t = tid >= off ? sh[tid - off] : 0;
        __syncthreads();
        sh[tid] += t;
        __syncthreads();
    }
    if (idx < NN) {
        int r0 = sh[tid] - s + boff[b];
        int4 r;
        r.x = r0; r.y = r0 + v.x; r.z = r.y + v.y; r.w = r.z + v.z;
        *(int4*)&row_ptr[idx] = r;
        *(int4*)&cursor[idx] = r;
    }
}

// place edges into CSR rows; fuses norm computation; packed (src, norm) 8B record
__global__ void k_place(const int* __restrict__ src, const int* __restrict__ dst,
                        const float* __restrict__ ew, const float* __restrict__ dinv,
                        int* __restrict__ cursor, int2* __restrict__ edges) {
    int e = blockIdx.x * blockDim.x + threadIdx.x;
    if (e >= NE) return;
    int d = dst[e];
    int s = src[e];
    int p = atomicAdd(&cursor[d], 1);
    float w = -dinv[s] * ew[e] * dinv[d];
    edges[p] = make_int2(s, __float_as_int(w));
}

// A1[n][j] = x[n]@W1[0][:,j];  B0[n][j] = x[n]@W1[1][:,j]
__global__ void k_mm1(const float* __restrict__ x, const float* __restrict__ W1,
                      float* __restrict__ A1, float* __restrict__ B0) {
    __shared__ float w[2 * FIN * HID];
    int tid = threadIdx.x;
    for (int i = tid; i < 2 * FIN * HID; i += 256) w[i] = W1[i];
    __syncthreads();
    int node = blockIdx.x * 8 + (tid >> 5);
    int c = tid & 31;
    int sel = c >> 4, jj = c & 15;
    if (node >= NN) return;
    const float* xr = x + node * FIN;
    const float* wp = w + sel * (FIN * HID) + jj;
    float acc = 0.f;
    #pragma unroll
    for (int f = 0; f < FIN; ++f) acc += xr[f] * wp[f * HID];
    if (sel == 0) A1[node * HID + jj] = acc;
    else          B0[node * HID + jj] = acc;
}

// wave per node, 4 edges x 16 feats per iteration, 2-way unroll.
// MODE 0: out = relu(A1 + acc + b1)   (layer-1, B = B0, out = h)
// MODE 1: out = acc                   (layer-2, B = h,  out = Th)
template <int MODE>
__global__ void k_gather(const int* __restrict__ row_ptr, const int2* __restrict__ edges,
                         const float* __restrict__ B,
                         const float* __restrict__ A1, const float* __restrict__ b1,
                         float* __restrict__ outb) {
    int node = blockIdx.x * 4 + (threadIdx.x >> 6);
    int lane = threadIdx.x & 63;
    int es = lane >> 4, j = lane & 15;
    if (node >= NN) return;
    int beg = row_ptr[node], end = row_ptr[node + 1];
    float acc = 0.f, acc2 = 0.f;
    int p = beg + es;
    for (; p + 4 < end; p += 8) {
        int2 a = edges[p];
        int2 b = edges[p + 4];
        acc  += __int_as_float(a.y) * B[a.x * HID + j];
        acc2 += __int_as_float(b.y) * B[b.x * HID + j];
    }
    if (p < end) {
        int2 a = edges[p];
        acc += __int_as_float(a.y) * B[a.x * HID + j];
    }
    acc += acc2;
    acc += __shfl_xor(acc, 16, 64);
    acc += __shfl_xor(acc, 32, 64);
    if (es == 0) {
        if (MODE == 0) {
            float v = A1[node * HID + j] + acc + b1[j];
            outb[node * HID + j] = fmaxf(v, 0.f);
        } else {
            outb[node * HID + j] = acc;
        }
    }
}

// fused: out[n][j] = lsm_j( h[n]@W2[0][:,j] + Th[n]@W2[1][:,j] + b2[j] )
__global__ void k_mm2_lsm(const float* __restrict__ h, const float* __restrict__ Th,
                          const float* __restrict__ W2, const float* __restrict__ b2,
                          float* __restrict__ out) {
    __shared__ float w[2 * HID * NC];  // 1280 floats
    int tid = threadIdx.x;
    for (int i = tid; i < 2 * HID * NC; i += 256) w[i] = W2[i];
    __syncthreads();
    int node = blockIdx.x * 4 + (tid >> 6);
    int lane = tid & 63;
    if (node >= NN) return;
    float v = -INFINITY;
    if (lane < NC) {
        const float* hr = h + node * HID;
        const float* tr = Th + node * HID;
        float acc = b2[lane];
        #pragma unroll
        for (int f = 0; f < HID; ++f) {
            acc += hr[f] * w[f * NC + lane];
            acc += tr[f] * w[HID * NC + f * NC + lane];
        }
        v = acc;
    }
    float m = v;
    #pragma unroll
    for (int s = 32; s > 0; s >>= 1) m = fmaxf(m, __shfl_xor(m, s, 64));
    float ex = (lane < NC) ? expf(v - m) : 0.f;
    float sum = ex;
    #pragma unroll
    for (int s = 32; s > 0; s >>= 1) sum += __shfl_xor(sum, s, 64);
    if (lane < NC) out[node * NC + lane] = v - m - logf(sum);
}

extern "C" void kernel_launch(void* const* d_in, const int* in_sizes, int n_in,
                              void* d_out, int out_size, void* d_ws, size_t ws_size,
                              hipStream_t stream) {
    const float* x  = (const float*)d_in[0];
    const float* ew = (const float*)d_in[1];
    const float* W1 = (const float*)d_in[2];
    const float* b1 = (const float*)d_in[3];
    const float* W2 = (const float*)d_in[4];
    const float* b2 = (const float*)d_in[5];
    const int*   ei = (const int*)d_in[6];
    const int* src = ei;
    const int* dst = ei + NE;
    float* out = (float*)d_out;

    const int NPAD = 100352;
    float* ws      = (float*)d_ws;
    float* deg     = ws;                       // NPAD f
    int*   cnt     = (int*)(deg + NPAD);       // NPAD i
    int*   row_ptr = cnt + NPAD;               // NPAD i (uses NN+1)
    int*   cursor  = row_ptr + NPAD;           // NPAD i
    int*   bsum    = cursor + NPAD;            // 128 i
    int*   boff    = bsum + 128;               // 128 i
    int2*  edges   = (int2*)(boff + 128);      // NE int2
    float* A1      = (float*)(edges + NE);     // NN*HID f
    float* B0      = A1 + NN * HID;            // NN*HID f
    float* h       = B0 + NN * HID;            // NN*HID f
    float* Th      = h + NN * HID;             // NN*HID f

    hipMemsetAsync(deg, 0, NPAD * sizeof(float), stream);
    hipMemsetAsync(cnt, 0, NPAD * sizeof(int), stream);

    k_deg_hist<<<(NE + 255) / 256, 256, 0, stream>>>(dst, ew, deg, cnt);
    k_dinv<<<(NN + 255) / 256, 256, 0, stream>>>(deg);
    k_scan1<<<NBLK, 256, 0, stream>>>(cnt, bsum);
    k_scan2<<<1, 128, 0, stream>>>(bsum, boff, row_ptr);
    k_scan3<<<NBLK, 256, 0, stream>>>(cnt, boff, row_ptr, cursor);
    k_place<<<(NE + 255) / 256, 256, 0, stream>>>(src, dst, ew, deg, cursor, edges);
    k_mm1<<<(NN + 7) / 8, 256, 0, stream>>>(x, W1, A1, B0);
    k_gather<0><<<(NN + 3) / 4, 256, 0, stream>>>(row_ptr, edges, B0, A1, b1, h);
    k_gather<1><<<(NN + 3) / 4, 256, 0, stream>>>(row_ptr, edges, h, nullptr, nullptr, Th);
    k_mm2_lsm<<<(NN + 3) / 4, 256, 0, stream>>>(h, Th, W2, b2, out);
}

// Round 5
// 321.715 us; speedup vs baseline: 2.4877x; 1.2541x over previous
//
#include <hip/hip_runtime.h>
#include <math.h>

#define NN 100000
#define NE 1600000
#define FIN 64
#define HID 16
#define NC 40

#define SCAN_CHUNK 1024
#define NBLK ((NN + SCAN_CHUNK - 1) / SCAN_CHUNK)  // 98

// packed[d] += (1 << 40) | fixpoint24(ew)   — one device atomic per edge
__global__ void k_hist(const int* __restrict__ dst, const float* __restrict__ ew,
                       unsigned long long* __restrict__ packed) {
    int e = blockIdx.x * blockDim.x + threadIdx.x;
    if (e < NE) {
        unsigned long long inc =
            (1ULL << 40) | (unsigned long long)(ew[e] * 16777216.0f);
        atomicAdd(&packed[dst[e]], inc);
    }
}

// unpack: cnt = hi24, deg = lo40 / 2^24 ; dinv = rsqrt(deg)
__global__ void k_dinv(const unsigned long long* __restrict__ packed,
                       float* __restrict__ dinv, int* __restrict__ cnt) {
    int i = blockIdx.x * blockDim.x + threadIdx.x;
    if (i < NN) {
        unsigned long long p = packed[i];
        int c = (int)(p >> 40);
        float d = (float)(p & ((1ULL << 40) - 1)) * (1.0f / 16777216.0f);
        dinv[i] = d > 0.f ? rsqrtf(fmaxf(d, 1e-30f)) : 0.f;
        cnt[i] = c;
    }
}

// phase 1: per-block sum of a 1024-int chunk of cnt
__global__ void k_scan1(const int* __restrict__ cnt, int* __restrict__ bsum) {
    __shared__ int red[4];
    int b = blockIdx.x, tid = threadIdx.x;
    int idx = b * SCAN_CHUNK + tid * 4;
    int s = 0;
    if (idx < NN) {
        int4 v = *(const int4*)&cnt[idx];
        s = v.x + v.y + v.z + v.w;
    }
    #pragma unroll
    for (int off = 32; off > 0; off >>= 1) s += __shfl_down(s, off, 64);
    if ((tid & 63) == 0) red[tid >> 6] = s;
    __syncthreads();
    if (tid == 0) bsum[b] = red[0] + red[1] + red[2] + red[3];
}

// phase 2: exclusive scan of the 98 block sums
__global__ void k_scan2(const int* __restrict__ bsum, int* __restrict__ boff,
                        int* __restrict__ row_ptr) {
    __shared__ int sh[128];
    int tid = threadIdx.x;
    int v = tid < NBLK ? bsum[tid] : 0;
    sh[tid] = v;
    __syncthreads();
    #pragma unroll
    for (int off = 1; off < 128; off <<= 1) {
        int t = tid >= off ? sh[tid - off] : 0;
        __syncthreads();
        sh[tid] += t;
        __syncthreads();
    }
    if (tid < NBLK) boff[tid] = sh[tid] - v;
    if (tid == 0) row_ptr[NN] = NE;
}

// phase 3: block-local exclusive scan + block offset -> row_ptr, cursor
__global__ void k_scan3(const int* __restrict__ cnt, const int* __restrict__ boff,
                        int* __restrict__ row_ptr, int* __restrict__ cursor) {
    __shared__ int sh[256];
    int b = blockIdx.x, tid = threadIdx.x;
    int idx = b * SCAN_CHUNK + tid * 4;
    int4 v = {0, 0, 0, 0};
    if (idx < NN) v = *(const int4*)&cnt[idx];
    int s = v.x + v.y + v.z + v.w;
    sh[tid] = s;
    __syncthreads();
    #pragma unroll
    for (int off = 1; off < 256; off <<= 1) {
        int t = tid >= off ? sh[tid - off] : 0;
        __syncthreads();
        sh[tid] += t;
        __syncthreads();
    }
    if (idx < NN) {
        int r0 = sh[tid] - s + boff[b];
        int4 r;
        r.x = r0; r.y = r0 + v.x; r.z = r.y + v.y; r.w = r.z + v.z;
        *(int4*)&row_ptr[idx] = r;
        *(int4*)&cursor[idx] = r;
    }
}

// place edges into CSR rows; fuses norm computation; packed (src, norm) 8B record
__global__ void k_place(const int* __restrict__ src, const int* __restrict__ dst,
                        const float* __restrict__ ew, const float* __restrict__ dinv,
                        int* __restrict__ cursor, int2* __restrict__ edges) {
    int e = blockIdx.x * blockDim.x + threadIdx.x;
    if (e >= NE) return;
    int d = dst[e];
    int s = src[e];
    int p = atomicAdd(&cursor[d], 1);
    float w = -dinv[s] * ew[e] * dinv[d];
    edges[p] = make_int2(s, __float_as_int(w));
}

// A1[n][j] = x[n]@W1[0][:,j];  B0[n][j] = x[n]@W1[1][:,j]
__global__ void k_mm1(const float* __restrict__ x, const float* __restrict__ W1,
                      float* __restrict__ A1, float* __restrict__ B0) {
    __shared__ float w[2 * FIN * HID];
    int tid = threadIdx.x;
    for (int i = tid; i < 2 * FIN * HID; i += 256) w[i] = W1[i];
    __syncthreads();
    int node = blockIdx.x * 8 + (tid >> 5);
    int c = tid & 31;
    int sel = c >> 4, jj = c & 15;
    if (node >= NN) return;
    const float* xr = x + node * FIN;
    const float* wp = w + sel * (FIN * HID) + jj;
    float acc = 0.f;
    #pragma unroll
    for (int f = 0; f < FIN; ++f) acc += xr[f] * wp[f * HID];
    if (sel == 0) A1[node * HID + jj] = acc;
    else          B0[node * HID + jj] = acc;
}

// wave per node, 4 edges x 16 feats per iteration, 2-way unroll.
// MODE 0: out = relu(A1 + acc + b1)   (layer-1, B = B0, out = h)
// MODE 1: out = acc                   (layer-2, B = h,  out = Th)
template <int MODE>
__global__ void k_gather(const int* __restrict__ row_ptr, const int2* __restrict__ edges,
                         const float* __restrict__ B,
                         const float* __restrict__ A1, const float* __restrict__ b1,
                         float* __restrict__ outb) {
    int node = blockIdx.x * 4 + (threadIdx.x >> 6);
    int lane = threadIdx.x & 63;
    int es = lane >> 4, j = lane & 15;
    if (node >= NN) return;
    int beg = row_ptr[node], end = row_ptr[node + 1];
    float acc = 0.f, acc2 = 0.f;
    int p = beg + es;
    for (; p + 4 < end; p += 8) {
        int2 a = edges[p];
        int2 b = edges[p + 4];
        acc  += __int_as_float(a.y) * B[a.x * HID + j];
        acc2 += __int_as_float(b.y) * B[b.x * HID + j];
    }
    if (p < end) {
        int2 a = edges[p];
        acc += __int_as_float(a.y) * B[a.x * HID + j];
    }
    acc += acc2;
    acc += __shfl_xor(acc, 16, 64);
    acc += __shfl_xor(acc, 32, 64);
    if (es == 0) {
        if (MODE == 0) {
            float v = A1[node * HID + j] + acc + b1[j];
            outb[node * HID + j] = fmaxf(v, 0.f);
        } else {
            outb[node * HID + j] = acc;
        }
    }
}

// fused: out[n][j] = lsm_j( h[n]@W2[0][:,j] + Th[n]@W2[1][:,j] + b2[j] )
__global__ void k_mm2_lsm(const float* __restrict__ h, const float* __restrict__ Th,
                          const float* __restrict__ W2, const float* __restrict__ b2,
                          float* __restrict__ out) {
    __shared__ float w[2 * HID * NC];  // 1280 floats
    int tid = threadIdx.x;
    for (int i = tid; i < 2 * HID * NC; i += 256) w[i] = W2[i];
    __syncthreads();
    int node = blockIdx.x * 4 + (tid >> 6);
    int lane = tid & 63;
    if (node >= NN) return;
    float v = -INFINITY;
    if (lane < NC) {
        const float* hr = h + node * HID;
        const float* tr = Th + node * HID;
        float acc = b2[lane];
        #pragma unroll
        for (int f = 0; f < HID; ++f) {
            acc += hr[f] * w[f * NC + lane];
            acc += tr[f] * w[HID * NC + f * NC + lane];
        }
        v = acc;
    }
    float m = v;
    #pragma unroll
    for (int s = 32; s > 0; s >>= 1) m = fmaxf(m, __shfl_xor(m, s, 64));
    float ex = (lane < NC) ? expf(v - m) : 0.f;
    float sum = ex;
    #pragma unroll
    for (int s = 32; s > 0; s >>= 1) sum += __shfl_xor(sum, s, 64);
    if (lane < NC) out[node * NC + lane] = v - m - logf(sum);
}

extern "C" void kernel_launch(void* const* d_in, const int* in_sizes, int n_in,
                              void* d_out, int out_size, void* d_ws, size_t ws_size,
                              hipStream_t stream) {
    const float* x  = (const float*)d_in[0];
    const float* ew = (const float*)d_in[1];
    const float* W1 = (const float*)d_in[2];
    const float* b1 = (const float*)d_in[3];
    const float* W2 = (const float*)d_in[4];
    const float* b2 = (const float*)d_in[5];
    const int*   ei = (const int*)d_in[6];
    const int* src = ei;
    const int* dst = ei + NE;
    float* out = (float*)d_out;

    const int NPAD = 100352;
    unsigned long long* packed = (unsigned long long*)d_ws;   // NPAD u64
    float* dinv    = (float*)(packed + NPAD);  // NPAD f
    int*   cnt     = (int*)(dinv + NPAD);      // NPAD i
    int*   row_ptr = cnt + NPAD;               // NPAD i (uses NN+1)
    int*   cursor  = row_ptr + NPAD;           // NPAD i
    int*   bsum    = cursor + NPAD;            // 128 i
    int*   boff    = bsum + 128;               // 128 i
    int2*  edges   = (int2*)(boff + 128);      // NE int2
    float* A1      = (float*)(edges + NE);     // NN*HID f
    float* B0      = A1 + NN * HID;            // NN*HID f
    float* h       = B0 + NN * HID;            // NN*HID f
    float* Th      = h + NN * HID;             // NN*HID f

    hipMemsetAsync(packed, 0, NPAD * sizeof(unsigned long long), stream);

    k_hist<<<(NE + 255) / 256, 256, 0, stream>>>(dst, ew, packed);
    k_dinv<<<(NN + 255) / 256, 256, 0, stream>>>(packed, dinv, cnt);
    k_scan1<<<NBLK, 256, 0, stream>>>(cnt, bsum);
    k_scan2<<<1, 128, 0, stream>>>(bsum, boff, row_ptr);
    k_scan3<<<NBLK, 256, 0, stream>>>(cnt, boff, row_ptr, cursor);
    k_place<<<(NE + 255) / 256, 256, 0, stream>>>(src, dst, ew, dinv, cursor, edges);
    k_mm1<<<(NN + 7) / 8, 256, 0, stream>>>(x, W1, A1, B0);
    k_gather<0><<<(NN + 3) / 4, 256, 0, stream>>>(row_ptr, edges, B0, A1, b1, h);
    k_gather<1><<<(NN + 3) / 4, 256, 0, stream>>>(row_ptr, edges, h, nullptr, nullptr, Th);
    k_mm2_lsm<<<(NN + 3) / 4, 256, 0, stream>>>(h, Th, W2, b2, out);
}

// Round 6
// 314.633 us; speedup vs baseline: 2.5437x; 1.0225x over previous
//
#include <hip/hip_runtime.h>
#include <math.h>

#define NN 100000
#define NE 1600000
#define FIN 64
#define HID 16
#define NC 40

#define SCAN_CHUNK 1024
#define NBLK ((NN + SCAN_CHUNK - 1) / SCAN_CHUNK)  // 98
#define NODES_PER_GRP 12500                        // NN / 8

// packed[d] += (1 << 40) | fixpoint24(ew); rank[e] = count before me
__global__ void k_hist(const int* __restrict__ dst, const float* __restrict__ ew,
                       unsigned long long* __restrict__ packed,
                       unsigned char* __restrict__ rank) {
    int e = blockIdx.x * blockDim.x + threadIdx.x;
    if (e < NE) {
        unsigned long long inc =
            (1ULL << 40) | (unsigned long long)(ew[e] * 16777216.0f);
        unsigned long long old = atomicAdd(&packed[dst[e]], inc);
        rank[e] = (unsigned char)(old >> 40);
    }
}

// unpack: cnt = hi24, deg = lo40 / 2^24 ; dinv = rsqrt(deg)
__global__ void k_dinv(const unsigned long long* __restrict__ packed,
                       float* __restrict__ dinv, int* __restrict__ cnt) {
    int i = blockIdx.x * blockDim.x + threadIdx.x;
    if (i < NN) {
        unsigned long long p = packed[i];
        int c = (int)(p >> 40);
        float d = (float)(p & ((1ULL << 40) - 1)) * (1.0f / 16777216.0f);
        dinv[i] = d > 0.f ? rsqrtf(fmaxf(d, 1e-30f)) : 0.f;
        cnt[i] = c;
    }
}

// phase 1: per-block sum of a 1024-int chunk of cnt
__global__ void k_scan1(const int* __restrict__ cnt, int* __restrict__ bsum) {
    __shared__ int red[4];
    int b = blockIdx.x, tid = threadIdx.x;
    int idx = b * SCAN_CHUNK + tid * 4;
    int s = 0;
    if (idx < NN) {
        int4 v = *(const int4*)&cnt[idx];
        s = v.x + v.y + v.z + v.w;
    }
    #pragma unroll
    for (int off = 32; off > 0; off >>= 1) s += __shfl_down(s, off, 64);
    if ((tid & 63) == 0) red[tid >> 6] = s;
    __syncthreads();
    if (tid == 0) bsum[b] = red[0] + red[1] + red[2] + red[3];
}

// phase 2: exclusive scan of the 98 block sums
__global__ void k_scan2(const int* __restrict__ bsum, int* __restrict__ boff,
                        int* __restrict__ row_ptr) {
    __shared__ int sh[128];
    int tid = threadIdx.x;
    int v = tid < NBLK ? bsum[tid] : 0;
    sh[tid] = v;
    __syncthreads();
    #pragma unroll
    for (int off = 1; off < 128; off <<= 1) {
        int t = tid >= off ? sh[tid - off] : 0;
        __syncthreads();
        sh[tid] += t;
        __syncthreads();
    }
    if (tid < NBLK) boff[tid] = sh[tid] - v;
    if (tid == 0) row_ptr[NN] = NE;
}

// phase 3: block-local exclusive scan + block offset -> row_ptr
__global__ void k_scan3(const int* __restrict__ cnt, const int* __restrict__ boff,
                        int* __restrict__ row_ptr) {
    __shared__ int sh[256];
    int b = blockIdx.x, tid = threadIdx.x;
    int idx = b * SCAN_CHUNK + tid * 4;
    int4 v = {0, 0, 0, 0};
    if (idx < NN) v = *(const int4*)&cnt[idx];
    int s = v.x + v.y + v.z + v.w;
    sh[tid] = s;
    __syncthreads();
    #pragma unroll
    for (int off = 1; off < 256; off <<= 1) {
        int t = tid >= off ? sh[tid - off] : 0;
        __syncthreads();
        sh[tid] += t;
        __syncthreads();
    }
    if (idx < NN) {
        int r0 = sh[tid] - s + boff[b];
        int4 r;
        r.x = r0; r.y = r0 + v.x; r.z = r.y + v.y; r.w = r.z + v.z;
        *(int4*)&row_ptr[idx] = r;
    }
}

// XCD-ownership placement, atomic-free: group g = bid&7 places only edges whose
// dst lies in its node range; p = row_ptr[d] + rank[e]. Writes stay in one
// contiguous ~1.6MB slice per group -> single-XCD L2 lines, no amplification.
#define PLACE_SUB 104  // blocks per group; grid = 8*104 = 832
__global__ void k_place_own(const int* __restrict__ src, const int* __restrict__ dst,
                            const float* __restrict__ ew,
                            const unsigned char* __restrict__ rank,
                            const float* __restrict__ dinv,
                            const int* __restrict__ row_ptr,
                            int2* __restrict__ edges) {
    int g = blockIdx.x & 7;
    int sub = blockIdx.x >> 3;
    int lo = g * NODES_PER_GRP, hi = lo + NODES_PER_GRP;
    int stride = PLACE_SUB * 256;
    for (int e = sub * 256 + threadIdx.x; e < NE; e += stride) {
        int d = dst[e];
        if (d >= lo && d < hi) {
            int s = src[e];
            float w = -dinv[s] * ew[e] * dinv[d];
            int p = row_ptr[d] + (int)rank[e];
            edges[p] = make_int2(s, __float_as_int(w));
        }
    }
}

// A1[n][j] = x[n]@W1[0][:,j];  B0[n][j] = x[n]@W1[1][:,j]
__global__ void k_mm1(const float* __restrict__ x, const float* __restrict__ W1,
                      float* __restrict__ A1, float* __restrict__ B0) {
    __shared__ float w[2 * FIN * HID];
    int tid = threadIdx.x;
    for (int i = tid; i < 2 * FIN * HID; i += 256) w[i] = W1[i];
    __syncthreads();
    int node = blockIdx.x * 8 + (tid >> 5);
    int c = tid & 31;
    int sel = c >> 4, jj = c & 15;
    if (node >= NN) return;
    const float* xr = x + node * FIN;
    const float* wp = w + sel * (FIN * HID) + jj;
    float acc = 0.f;
    #pragma unroll
    for (int f = 0; f < FIN; ++f) acc += xr[f] * wp[f * HID];
    if (sel == 0) A1[node * HID + jj] = acc;
    else          B0[node * HID + jj] = acc;
}

// wave per node, 4 edge-slots x 16 feats, 4-way unroll (16 loads in flight).
// MODE 0: out = relu(A1 + acc + b1)   (layer-1, B = B0, out = h)
// MODE 1: out = acc                   (layer-2, B = h,  out = Th)
template <int MODE>
__global__ void k_gather(const int* __restrict__ row_ptr, const int2* __restrict__ edges,
                         const float* __restrict__ B,
                         const float* __restrict__ A1, const float* __restrict__ b1,
                         float* __restrict__ outb) {
    int node = blockIdx.x * 4 + (threadIdx.x >> 6);
    int lane = threadIdx.x & 63;
    int es = lane >> 4, j = lane & 15;
    if (node >= NN) return;
    int beg = row_ptr[node], end = row_ptr[node + 1];
    float a0 = 0.f, a1 = 0.f, a2 = 0.f, a3 = 0.f;
    int p = beg + es;
    for (; p + 12 < end; p += 16) {
        int2 ea = edges[p];
        int2 eb = edges[p + 4];
        int2 ec = edges[p + 8];
        int2 ed = edges[p + 12];
        a0 += __int_as_float(ea.y) * B[ea.x * HID + j];
        a1 += __int_as_float(eb.y) * B[eb.x * HID + j];
        a2 += __int_as_float(ec.y) * B[ec.x * HID + j];
        a3 += __int_as_float(ed.y) * B[ed.x * HID + j];
    }
    for (; p < end; p += 4) {
        int2 ea = edges[p];
        a0 += __int_as_float(ea.y) * B[ea.x * HID + j];
    }
    float acc = (a0 + a1) + (a2 + a3);
    acc += __shfl_xor(acc, 16, 64);
    acc += __shfl_xor(acc, 32, 64);
    if (es == 0) {
        if (MODE == 0) {
            float v = A1[node * HID + j] + acc + b1[j];
            outb[node * HID + j] = fmaxf(v, 0.f);
        } else {
            outb[node * HID + j] = acc;
        }
    }
}

// fused: out[n][j] = lsm_j( h[n]@W2[0][:,j] + Th[n]@W2[1][:,j] + b2[j] )
__global__ void k_mm2_lsm(const float* __restrict__ h, const float* __restrict__ Th,
                          const float* __restrict__ W2, const float* __restrict__ b2,
                          float* __restrict__ out) {
    __shared__ float w[2 * HID * NC];
    int tid = threadIdx.x;
    for (int i = tid; i < 2 * HID * NC; i += 256) w[i] = W2[i];
    __syncthreads();
    int node = blockIdx.x * 4 + (tid >> 6);
    int lane = tid & 63;
    if (node >= NN) return;
    float v = -INFINITY;
    if (lane < NC) {
        const float* hr = h + node * HID;
        const float* tr = Th + node * HID;
        float acc = b2[lane];
        #pragma unroll
        for (int f = 0; f < HID; ++f) {
            acc += hr[f] * w[f * NC + lane];
            acc += tr[f] * w[HID * NC + f * NC + lane];
        }
        v = acc;
    }
    float m = v;
    #pragma unroll
    for (int s = 32; s > 0; s >>= 1) m = fmaxf(m, __shfl_xor(m, s, 64));
    float ex = (lane < NC) ? expf(v - m) : 0.f;
    float sum = ex;
    #pragma unroll
    for (int s = 32; s > 0; s >>= 1) sum += __shfl_xor(sum, s, 64);
    if (lane < NC) out[node * NC + lane] = v - m - logf(sum);
}

extern "C" void kernel_launch(void* const* d_in, const int* in_sizes, int n_in,
                              void* d_out, int out_size, void* d_ws, size_t ws_size,
                              hipStream_t stream) {
    const float* x  = (const float*)d_in[0];
    const float* ew = (const float*)d_in[1];
    const float* W1 = (const float*)d_in[2];
    const float* b1 = (const float*)d_in[3];
    const float* W2 = (const float*)d_in[4];
    const float* b2 = (const float*)d_in[5];
    const int*   ei = (const int*)d_in[6];
    const int* src = ei;
    const int* dst = ei + NE;
    float* out = (float*)d_out;

    const int NPAD = 100352;
    unsigned long long* packed = (unsigned long long*)d_ws;  // NPAD u64
    int2*  edges   = (int2*)(packed + NPAD);   // NE int2 (8B aligned)
    float* A1      = (float*)(edges + NE);     // NN*HID f
    float* B0      = A1 + NN * HID;            // NN*HID f
    float* h       = B0 + NN * HID;            // NN*HID f
    float* Th      = h + NN * HID;             // NN*HID f
    float* dinv    = Th + NN * HID;            // NPAD f
    int*   cnt     = (int*)(dinv + NPAD);      // NPAD i
    int*   row_ptr = cnt + NPAD;               // NPAD i (uses NN+1)
    int*   bsum    = row_ptr + NPAD;           // 128 i
    int*   boff    = bsum + 128;               // 128 i
    unsigned char* rank = (unsigned char*)(boff + 128);  // NE u8

    hipMemsetAsync(packed, 0, NPAD * sizeof(unsigned long long), stream);

    k_hist<<<(NE + 255) / 256, 256, 0, stream>>>(dst, ew, packed, rank);
    k_dinv<<<(NN + 255) / 256, 256, 0, stream>>>(packed, dinv, cnt);
    k_scan1<<<NBLK, 256, 0, stream>>>(cnt, bsum);
    k_scan2<<<1, 128, 0, stream>>>(bsum, boff, row_ptr);
    k_scan3<<<NBLK, 256, 0, stream>>>(cnt, boff, row_ptr);
    k_place_own<<<8 * PLACE_SUB, 256, 0, stream>>>(src, dst, ew, rank, dinv,
                                                   row_ptr, edges);
    k_mm1<<<(NN + 7) / 8, 256, 0, stream>>>(x, W1, A1, B0);
    k_gather<0><<<(NN + 3) / 4, 256, 0, stream>>>(row_ptr, edges, B0, A1, b1, h);
    k_gather<1><<<(NN + 3) / 4, 256, 0, stream>>>(row_ptr, edges, h, nullptr, nullptr, Th);
    k_mm2_lsm<<<(NN + 3) / 4, 256, 0, stream>>>(h, Th, W2, b2, out);
}

// Round 7
// 252.688 us; speedup vs baseline: 3.1673x; 1.2451x over previous
//
#include <hip/hip_runtime.h>
#include <math.h>

#define NN 100000
#define NE 1600000
#define FIN 64
#define HID 16
#define NC 40

#define NG 64       // dst-range groups (buckets)
#define GN 1563     // nodes per group: 64*1563 = 100032 >= NN
#define GCAP 26000  // staging capacity per bucket (expect 25000 +- 157)

#define SCAN_CHUNK 1024
#define NBLK ((NN + SCAN_CHUNK - 1) / SCAN_CHUNK)  // 98

typedef unsigned int u32;
typedef unsigned long long u64;

// ---- phase 1: bucket scatter (no per-edge global atomics) ----
// staging record: hi32 = local_d, lo32 = s | (ewq15 << 17)
__global__ void k_bucket(const int* __restrict__ src, const int* __restrict__ dst,
                         const float* __restrict__ ew,
                         int* __restrict__ bcur,  // 64 cursors padded 16-stride
                         u64* __restrict__ stg) {
    __shared__ int lcnt[NG];
    __shared__ int lpos[NG];
    int tid = threadIdx.x;
    if (tid < NG) lcnt[tid] = 0;
    __syncthreads();
    int g[4];
    u64 rec[4];
    int e0 = blockIdx.x * 1024 + tid;
    #pragma unroll
    for (int k = 0; k < 4; ++k) {
        int e = e0 + k * 256;
        g[k] = -1;
        if (e < NE) {
            int d = dst[e];
            int s = src[e];
            u32 q = (u32)fminf(ew[e] * 32767.f + 0.5f, 32767.f);
            int gg = d / GN;
            g[k] = gg;
            rec[k] = ((u64)(d - gg * GN) << 32) | (u64)(u32)(s | (q << 17));
            atomicAdd(&lcnt[gg], 1);
        }
    }
    __syncthreads();
    if (tid < NG) lpos[tid] = atomicAdd(&bcur[tid << 4], lcnt[tid]);
    __syncthreads();
    #pragma unroll
    for (int k = 0; k < 4; ++k) {
        if (g[k] >= 0) {
            int slot = atomicAdd(&lpos[g[k]], 1);
            if (slot < GCAP) stg[(size_t)g[k] * GCAP + slot] = rec[k];
        }
    }
}

// ---- phase 2A: per-group LDS histogram -> cnt, dinv (no global atomics) ----
__global__ void __launch_bounds__(256) k_hist_own(const u64* __restrict__ stg,
                                                  const int* __restrict__ bcur,
                                                  int* __restrict__ cnt,
                                                  float* __restrict__ dinv) {
    __shared__ u32 hc[GN];
    __shared__ u32 hw[GN];
    int g = blockIdx.x, tid = threadIdx.x;
    for (int i = tid; i < GN; i += 256) { hc[i] = 0; hw[i] = 0; }
    __syncthreads();
    int n = bcur[g << 4];
    const u64* base = stg + (size_t)g * GCAP;
    int i = tid;
    for (; i + 768 < n; i += 1024) {
        u64 r0 = base[i], r1 = base[i + 256], r2 = base[i + 512], r3 = base[i + 768];
        atomicAdd(&hc[(int)(r0 >> 32)], 1u); atomicAdd(&hw[(int)(r0 >> 32)], ((u32)r0) >> 17);
        atomicAdd(&hc[(int)(r1 >> 32)], 1u); atomicAdd(&hw[(int)(r1 >> 32)], ((u32)r1) >> 17);
        atomicAdd(&hc[(int)(r2 >> 32)], 1u); atomicAdd(&hw[(int)(r2 >> 32)], ((u32)r2) >> 17);
        atomicAdd(&hc[(int)(r3 >> 32)], 1u); atomicAdd(&hw[(int)(r3 >> 32)], ((u32)r3) >> 17);
    }
    for (; i < n; i += 256) {
        u64 r = base[i];
        atomicAdd(&hc[(int)(r >> 32)], 1u); atomicAdd(&hw[(int)(r >> 32)], ((u32)r) >> 17);
    }
    __syncthreads();
    int n0 = g * GN;
    for (int k = tid; k < GN; k += 256) {
        if (n0 + k < NN) {
            float deg = (float)hw[k] * (1.0f / 32767.0f);
            cnt[n0 + k] = (int)hc[k];
            dinv[n0 + k] = deg > 0.f ? rsqrtf(fmaxf(deg, 1e-30f)) : 0.f;
        }
    }
}

// ---- scans (unchanged 3-phase) ----
__global__ void k_scan1(const int* __restrict__ cnt, int* __restrict__ bsum) {
    __shared__ int red[4];
    int b = blockIdx.x, tid = threadIdx.x;
    int idx = b * SCAN_CHUNK + tid * 4;
    int s = 0;
    if (idx < NN) {
        int4 v = *(const int4*)&cnt[idx];
        s = v.x + v.y + v.z + v.w;
    }
    #pragma unroll
    for (int off = 32; off > 0; off >>= 1) s += __shfl_down(s, off, 64);
    if ((tid & 63) == 0) red[tid >> 6] = s;
    __syncthreads();
    if (tid == 0) bsum[b] = red[0] + red[1] + red[2] + red[3];
}

__global__ void k_scan2(const int* __restrict__ bsum, int* __restrict__ boff,
                        int* __restrict__ row_ptr) {
    __shared__ int sh[128];
    int tid = threadIdx.x;
    int v = tid < NBLK ? bsum[tid] : 0;
    sh[tid] = v;
    __syncthreads();
    #pragma unroll
    for (int off = 1; off < 128; off <<= 1) {
        int t = tid >= off ? sh[tid - off] : 0;
        __syncthreads();
        sh[tid] += t;
        __syncthreads();
    }
    if (tid < NBLK) boff[tid] = sh[tid] - v;
    if (tid == 0) row_ptr[NN] = NE;
}

__global__ void k_scan3(const int* __restrict__ cnt, const int* __restrict__ boff,
                        int* __restrict__ row_ptr) {
    __shared__ int sh[256];
    int b = blockIdx.x, tid = threadIdx.x;
    int idx = b * SCAN_CHUNK + tid * 4;
    int4 v = {0, 0, 0, 0};
    if (idx < NN) v = *(const int4*)&cnt[idx];
    int s = v.x + v.y + v.z + v.w;
    sh[tid] = s;
    __syncthreads();
    #pragma unroll
    for (int off = 1; off < 256; off <<= 1) {
        int t = tid >= off ? sh[tid - off] : 0;
        __syncthreads();
        sh[tid] += t;
        __syncthreads();
    }
    if (idx < NN) {
        int r0 = sh[tid] - s + boff[b];
        int4 r;
        r.x = r0; r.y = r0 + v.x; r.z = r.y + v.y; r.w = r.z + v.z;
        *(int4*)&row_ptr[idx] = r;
    }
}

// ---- phase 2B: per-group placement via LDS cursors; 4B final records ----
__global__ void __launch_bounds__(256) k_place2(const u64* __restrict__ stg,
                                                const int* __restrict__ bcur,
                                                const int* __restrict__ row_ptr,
                                                u32* __restrict__ edges4) {
    __shared__ int cur[GN];
    int g = blockIdx.x, tid = threadIdx.x;
    int n0 = g * GN;
    for (int i = tid; i < GN; i += 256) cur[i] = (n0 + i < NN) ? row_ptr[n0 + i] : 0;
    __syncthreads();
    int n = bcur[g << 4];
    const u64* base = stg + (size_t)g * GCAP;
    int i = tid;
    for (; i + 768 < n; i += 1024) {
        u64 r0 = base[i], r1 = base[i + 256], r2 = base[i + 512], r3 = base[i + 768];
        edges4[atomicAdd(&cur[(int)(r0 >> 32)], 1)] = (u32)r0;
        edges4[atomicAdd(&cur[(int)(r1 >> 32)], 1)] = (u32)r1;
        edges4[atomicAdd(&cur[(int)(r2 >> 32)], 1)] = (u32)r2;
        edges4[atomicAdd(&cur[(int)(r3 >> 32)], 1)] = (u32)r3;
    }
    for (; i < n; i += 256) {
        u64 r = base[i];
        edges4[atomicAdd(&cur[(int)(r >> 32)], 1)] = (u32)r;
    }
}

// A1[n][j] = x[n]@W1[0][:,j];  B0p[n][j] = dinv[n] * (x[n]@W1[1][:,j])
__global__ void k_mm1(const float* __restrict__ x, const float* __restrict__ W1,
                      const float* __restrict__ dinv,
                      float* __restrict__ A1, float* __restrict__ B0p) {
    __shared__ float w[2 * FIN * HID];
    int tid = threadIdx.x;
    for (int i = tid; i < 2 * FIN * HID; i += 256) w[i] = W1[i];
    __syncthreads();
    int node = blockIdx.x * 8 + (tid >> 5);
    int c = tid & 31;
    int sel = c >> 4, jj = c & 15;
    if (node >= NN) return;
    const float* xr = x + node * FIN;
    const float* wp = w + sel * (FIN * HID) + jj;
    float acc = 0.f;
    #pragma unroll
    for (int f = 0; f < FIN; ++f) acc += xr[f] * wp[f * HID];
    if (sel == 0) A1[node * HID + jj] = acc;
    else          B0p[node * HID + jj] = acc * dinv[node];
}

// wave per node, 4 edge-slots x 16 feats, 4-way unroll, 4B records.
// MODE 0: h = relu(A1 - dinv*acc + b1); h2 = h*dinv   (B = B0p)
// MODE 1: Th = -dinv*acc                               (B = h2)
template <int MODE>
__global__ void k_gather(const int* __restrict__ row_ptr, const u32* __restrict__ edges4,
                         const float* __restrict__ B,
                         const float* __restrict__ A1, const float* __restrict__ b1,
                         const float* __restrict__ dinv,
                         float* __restrict__ o1, float* __restrict__ o2) {
    int node = blockIdx.x * 4 + (threadIdx.x >> 6);
    int lane = threadIdx.x & 63;
    int es = lane >> 4, j = lane & 15;
    if (node >= NN) return;
    int beg = row_ptr[node], end = row_ptr[node + 1];
    float a0 = 0.f, a1v = 0.f, a2 = 0.f, a3 = 0.f;
    int p = beg + es;
    for (; p + 12 < end; p += 16) {
        u32 r0 = edges4[p];
        u32 r1 = edges4[p + 4];
        u32 r2 = edges4[p + 8];
        u32 r3 = edges4[p + 12];
        a0  += (float)(r0 >> 17) * B[(r0 & 0x1FFFF) * HID + j];
        a1v += (float)(r1 >> 17) * B[(r1 & 0x1FFFF) * HID + j];
        a2  += (float)(r2 >> 17) * B[(r2 & 0x1FFFF) * HID + j];
        a3  += (float)(r3 >> 17) * B[(r3 & 0x1FFFF) * HID + j];
    }
    for (; p < end; p += 4) {
        u32 r = edges4[p];
        a0 += (float)(r >> 17) * B[(r & 0x1FFFF) * HID + j];
    }
    float acc = ((a0 + a1v) + (a2 + a3)) * (1.0f / 32767.0f);
    acc += __shfl_xor(acc, 16, 64);
    acc += __shfl_xor(acc, 32, 64);
    if (es == 0) {
        float di = dinv[node];
        if (MODE == 0) {
            float v = A1[node * HID + j] - di * acc + b1[j];
            float hh = fmaxf(v, 0.f);
            o1[node * HID + j] = hh;
            o2[node * HID + j] = hh * di;
        } else {
            o1[node * HID + j] = -di * acc;
        }
    }
}

// fused: out[n][j] = lsm_j( h[n]@W2[0][:,j] + Th[n]@W2[1][:,j] + b2[j] )
__global__ void k_mm2_lsm(const float* __restrict__ h, const float* __restrict__ Th,
                          const float* __restrict__ W2, const float* __restrict__ b2,
                          float* __restrict__ out) {
    __shared__ float w[2 * HID * NC];
    int tid = threadIdx.x;
    for (int i = tid; i < 2 * HID * NC; i += 256) w[i] = W2[i];
    __syncthreads();
    int node = blockIdx.x * 4 + (tid >> 6);
    int lane = tid & 63;
    if (node >= NN) return;
    float v = -INFINITY;
    if (lane < NC) {
        const float* hr = h + node * HID;
        const float* tr = Th + node * HID;
        float acc = b2[lane];
        #pragma unroll
        for (int f = 0; f < HID; ++f) {
            acc += hr[f] * w[f * NC + lane];
            acc += tr[f] * w[HID * NC + f * NC + lane];
        }
        v = acc;
    }
    float m = v;
    #pragma unroll
    for (int s = 32; s > 0; s >>= 1) m = fmaxf(m, __shfl_xor(m, s, 64));
    float ex = (lane < NC) ? expf(v - m) : 0.f;
    float sum = ex;
    #pragma unroll
    for (int s = 32; s > 0; s >>= 1) sum += __shfl_xor(sum, s, 64);
    if (lane < NC) out[node * NC + lane] = v - m - logf(sum);
}

extern "C" void kernel_launch(void* const* d_in, const int* in_sizes, int n_in,
                              void* d_out, int out_size, void* d_ws, size_t ws_size,
                              hipStream_t stream) {
    const float* x  = (const float*)d_in[0];
    const float* ew = (const float*)d_in[1];
    const float* W1 = (const float*)d_in[2];
    const float* b1 = (const float*)d_in[3];
    const float* W2 = (const float*)d_in[4];
    const float* b2 = (const float*)d_in[5];
    const int*   ei = (const int*)d_in[6];
    const int* src = ei;
    const int* dst = ei + NE;
    float* out = (float*)d_out;

    const int NPAD = 100352;
    int*   bcur    = (int*)d_ws;                       // 64*16 i (padded cursors)
    u64*   stg     = (u64*)(bcur + 1024);              // NG*GCAP u64 (~13.3MB)
    u32*   edges4  = (u32*)(stg + (size_t)NG * GCAP);  // NE u32 (6.4MB)
    int*   cnt     = (int*)(edges4 + NE);              // NPAD i
    int*   row_ptr = cnt + NPAD;                       // NPAD i (uses NN+1)
    int*   bsum    = row_ptr + NPAD;                   // 128 i
    int*   boff    = bsum + 128;                       // 128 i
    float* dinv    = (float*)(boff + 128);             // NPAD f
    float* A1      = dinv + NPAD;                      // NN*HID f
    float* B0p     = A1 + NN * HID;                    // NN*HID f
    float* h       = B0p + NN * HID;                   // NN*HID f
    float* h2      = h + NN * HID;                     // NN*HID f
    float* Th      = h2 + NN * HID;                    // NN*HID f

    hipMemsetAsync(bcur, 0, 1024 * sizeof(int), stream);

    k_bucket<<<(NE + 1023) / 1024, 256, 0, stream>>>(src, dst, ew, bcur, stg);
    k_hist_own<<<NG, 256, 0, stream>>>(stg, bcur, cnt, dinv);
    k_scan1<<<NBLK, 256, 0, stream>>>(cnt, bsum);
    k_scan2<<<1, 128, 0, stream>>>(bsum, boff, row_ptr);
    k_scan3<<<NBLK, 256, 0, stream>>>(cnt, boff, row_ptr);
    k_place2<<<NG, 256, 0, stream>>>(stg, bcur, row_ptr, edges4);
    k_mm1<<<(NN + 7) / 8, 256, 0, stream>>>(x, W1, dinv, A1, B0p);
    k_gather<0><<<(NN + 3) / 4, 256, 0, stream>>>(row_ptr, edges4, B0p, A1, b1, dinv, h, h2);
    k_gather<1><<<(NN + 3) / 4, 256, 0, stream>>>(row_ptr, edges4, h2, nullptr, nullptr, dinv, Th, nullptr);
    k_mm2_lsm<<<(NN + 3) / 4, 256, 0, stream>>>(h, Th, W2, b2, out);
}

// Round 8
// 213.090 us; speedup vs baseline: 3.7558x; 1.1858x over previous
//
#include <hip/hip_runtime.h>
#include <math.h>

#define NN 100000
#define NE 1600000
#define FIN 64
#define HID 16
#define NC 40

#define NG 64       // dst-range groups (buckets)
#define GN 1563     // nodes per group: 64*1563 = 100032 >= NN
#define GCAP 26000  // staging capacity per bucket (expect ~25000)
#define CHB 7       // scan chunk per thread: 7*256 = 1792 >= GN

typedef unsigned int u32;
typedef unsigned long long u64;

// ---- phase 1: bucket scatter (no per-edge global atomics) ----
// staging record: hi32 = local_d, lo32 = s | (ewq15 << 17)
__global__ void k_bucket(const int* __restrict__ src, const int* __restrict__ dst,
                         const float* __restrict__ ew,
                         int* __restrict__ bcur,  // 64 cursors padded 16-stride
                         u64* __restrict__ stg) {
    __shared__ int lcnt[NG];
    __shared__ int lpos[NG];
    int tid = threadIdx.x;
    if (tid < NG) lcnt[tid] = 0;
    __syncthreads();
    int g[4];
    u64 rec[4];
    int e0 = blockIdx.x * 1024 + tid;
    #pragma unroll
    for (int k = 0; k < 4; ++k) {
        int e = e0 + k * 256;
        g[k] = -1;
        if (e < NE) {
            int d = dst[e];
            int s = src[e];
            u32 q = (u32)fminf(ew[e] * 32767.f + 0.5f, 32767.f);
            int gg = d / GN;
            g[k] = gg;
            rec[k] = ((u64)(d - gg * GN) << 32) | (u64)(u32)(s | (q << 17));
            atomicAdd(&lcnt[gg], 1);
        }
    }
    __syncthreads();
    if (tid < NG) lpos[tid] = atomicAdd(&bcur[tid << 4], lcnt[tid]);
    __syncthreads();
    #pragma unroll
    for (int k = 0; k < 4; ++k) {
        if (g[k] >= 0) {
            int slot = atomicAdd(&lpos[g[k]], 1);
            if (slot < GCAP) stg[(size_t)g[k] * GCAP + slot] = rec[k];
        }
    }
}

// ---- fused builder: hist + scan + row_ptr/dinv + placement, one block per group ----
__global__ void __launch_bounds__(256) k_build(const u64* __restrict__ stg,
                                               const int* __restrict__ bcur,
                                               int* __restrict__ row_ptr,
                                               float* __restrict__ dinv,
                                               u32* __restrict__ edges4) {
    __shared__ u32 hc[GN];   // counts, then reused as cursors
    __shared__ u32 hw[GN];   // fixed-point weighted degree
    __shared__ int tsum[256];
    __shared__ int sbc[NG];
    __shared__ int gbase;
    int g = blockIdx.x, tid = threadIdx.x;
    for (int i = tid; i < GN; i += 256) { hc[i] = 0; hw[i] = 0; }
    if (tid < NG) sbc[tid] = bcur[tid << 4];
    __syncthreads();
    int n = sbc[g];
    const u64* base = stg + (size_t)g * GCAP;
    // pass 1: histogram via LDS atomics
    int i = tid;
    for (; i + 768 < n; i += 1024) {
        u64 r0 = base[i], r1 = base[i + 256], r2 = base[i + 512], r3 = base[i + 768];
        atomicAdd(&hc[(int)(r0 >> 32)], 1u); atomicAdd(&hw[(int)(r0 >> 32)], ((u32)r0) >> 17);
        atomicAdd(&hc[(int)(r1 >> 32)], 1u); atomicAdd(&hw[(int)(r1 >> 32)], ((u32)r1) >> 17);
        atomicAdd(&hc[(int)(r2 >> 32)], 1u); atomicAdd(&hw[(int)(r2 >> 32)], ((u32)r2) >> 17);
        atomicAdd(&hc[(int)(r3 >> 32)], 1u); atomicAdd(&hw[(int)(r3 >> 32)], ((u32)r3) >> 17);
    }
    for (; i < n; i += 256) {
        u64 r = base[i];
        atomicAdd(&hc[(int)(r >> 32)], 1u); atomicAdd(&hw[(int)(r >> 32)], ((u32)r) >> 17);
    }
    __syncthreads();
    // group base = prefix of bucket counts
    if (tid == 0) {
        int off = 0;
        for (int q = 0; q < g; ++q) off += sbc[q];
        gbase = off;
    }
    // block scan over hc
    int k0 = tid * CHB;
    u32 loc[CHB];
    int s = 0;
    #pragma unroll
    for (int q = 0; q < CHB; ++q) {
        int k = k0 + q;
        loc[q] = (k < GN) ? hc[k] : 0;
        s += (int)loc[q];
    }
    tsum[tid] = s;
    __syncthreads();
    #pragma unroll
    for (int off = 1; off < 256; off <<= 1) {
        int t = tid >= off ? tsum[tid - off] : 0;
        __syncthreads();
        tsum[tid] += t;
        __syncthreads();
    }
    int run = gbase + tsum[tid] - s;
    int n0 = g * GN;
    #pragma unroll
    for (int q = 0; q < CHB; ++q) {
        int k = k0 + q;
        if (k < GN) {
            int nd = n0 + k;
            if (nd <= NN) row_ptr[nd] = run;   // nd==NN writes row_ptr[NN]=NE
            if (nd < NN) {
                float deg = (float)hw[k] * (1.0f / 32767.0f);
                dinv[nd] = deg > 0.f ? rsqrtf(fmaxf(deg, 1e-30f)) : 0.f;
            }
            hc[k] = (u32)run;   // cursor for pass 2
            run += (int)loc[q];
        }
    }
    __syncthreads();
    // pass 2: place (4B records) via LDS cursors into this group's CSR slice
    i = tid;
    for (; i + 768 < n; i += 1024) {
        u64 r0 = base[i], r1 = base[i + 256], r2 = base[i + 512], r3 = base[i + 768];
        edges4[atomicAdd(&hc[(int)(r0 >> 32)], 1u)] = (u32)r0;
        edges4[atomicAdd(&hc[(int)(r1 >> 32)], 1u)] = (u32)r1;
        edges4[atomicAdd(&hc[(int)(r2 >> 32)], 1u)] = (u32)r2;
        edges4[atomicAdd(&hc[(int)(r3 >> 32)], 1u)] = (u32)r3;
    }
    for (; i < n; i += 256) {
        u64 r = base[i];
        edges4[atomicAdd(&hc[(int)(r >> 32)], 1u)] = (u32)r;
    }
}

// A1[n][j] = x[n]@W1[0][:,j];  B0p[n][j] = dinv[n] * (x[n]@W1[1][:,j])
__global__ void k_mm1(const float* __restrict__ x, const float* __restrict__ W1,
                      const float* __restrict__ dinv,
                      float* __restrict__ A1, float* __restrict__ B0p) {
    __shared__ float w[2 * FIN * HID];
    int tid = threadIdx.x;
    for (int i = tid; i < 2 * FIN * HID; i += 256) w[i] = W1[i];
    __syncthreads();
    int node = blockIdx.x * 8 + (tid >> 5);
    int c = tid & 31;
    int sel = c >> 4, jj = c & 15;
    if (node >= NN) return;
    const float* xr = x + node * FIN;
    const float* wp = w + sel * (FIN * HID) + jj;
    float acc = 0.f;
    #pragma unroll
    for (int f = 0; f < FIN; ++f) acc += xr[f] * wp[f * HID];
    if (sel == 0) A1[node * HID + jj] = acc;
    else          B0p[node * HID + jj] = acc * dinv[node];
}

// wave per node, 4 edge-slots x 16 feats, 4-way unroll, 4B records.
// MODE 0: h = relu(A1 - dinv*acc + b1); h2 = h*dinv   (B = B0p)
// MODE 1: Th = -dinv*acc                               (B = h2)
template <int MODE>
__global__ void k_gather(const int* __restrict__ row_ptr, const u32* __restrict__ edges4,
                         const float* __restrict__ B,
                         const float* __restrict__ A1, const float* __restrict__ b1,
                         const float* __restrict__ dinv,
                         float* __restrict__ o1, float* __restrict__ o2) {
    int node = blockIdx.x * 4 + (threadIdx.x >> 6);
    int lane = threadIdx.x & 63;
    int es = lane >> 4, j = lane & 15;
    if (node >= NN) return;
    int beg = row_ptr[node], end = row_ptr[node + 1];
    float a0 = 0.f, a1v = 0.f, a2 = 0.f, a3 = 0.f;
    int p = beg + es;
    for (; p + 12 < end; p += 16) {
        u32 r0 = edges4[p];
        u32 r1 = edges4[p + 4];
        u32 r2 = edges4[p + 8];
        u32 r3 = edges4[p + 12];
        a0  += (float)(r0 >> 17) * B[(r0 & 0x1FFFF) * HID + j];
        a1v += (float)(r1 >> 17) * B[(r1 & 0x1FFFF) * HID + j];
        a2  += (float)(r2 >> 17) * B[(r2 & 0x1FFFF) * HID + j];
        a3  += (float)(r3 >> 17) * B[(r3 & 0x1FFFF) * HID + j];
    }
    for (; p < end; p += 4) {
        u32 r = edges4[p];
        a0 += (float)(r >> 17) * B[(r & 0x1FFFF) * HID + j];
    }
    float acc = ((a0 + a1v) + (a2 + a3)) * (1.0f / 32767.0f);
    acc += __shfl_xor(acc, 16, 64);
    acc += __shfl_xor(acc, 32, 64);
    if (es == 0) {
        float di = dinv[node];
        if (MODE == 0) {
            float v = A1[node * HID + j] - di * acc + b1[j];
            float hh = fmaxf(v, 0.f);
            o1[node * HID + j] = hh;
            o2[node * HID + j] = hh * di;
        } else {
            o1[node * HID + j] = -di * acc;
        }
    }
}

// thread-per-node: logits in regs, W2 broadcast from LDS, native exp/log
__global__ void __launch_bounds__(256) k_mm2_lsm(const float* __restrict__ h,
                                                 const float* __restrict__ Th,
                                                 const float* __restrict__ W2,
                                                 const float* __restrict__ b2,
                                                 float* __restrict__ out) {
    __shared__ float4 w4[32][10];  // [f' = sel*16+f][ctile]; W2 flat = f'*40 + c
    __shared__ float sb2[NC];
    int tid = threadIdx.x;
    for (int i = tid; i < 320; i += 256) {
        int f = i / 10, ct = i % 10;
        w4[f][ct] = *(const float4*)(W2 + f * 40 + ct * 4);
    }
    for (int i = tid; i < NC; i += 256) sb2[i] = b2[i];
    __syncthreads();
    int node = blockIdx.x * 256 + tid;
    if (node >= NN) return;
    float v[32];
    const float4* hp = (const float4*)(h + node * HID);
    const float4* tp = (const float4*)(Th + node * HID);
    #pragma unroll
    for (int q = 0; q < 4; ++q) {
        float4 a = hp[q];
        v[4 * q + 0] = a.x; v[4 * q + 1] = a.y; v[4 * q + 2] = a.z; v[4 * q + 3] = a.w;
        float4 b = tp[q];
        v[16 + 4 * q + 0] = b.x; v[16 + 4 * q + 1] = b.y; v[16 + 4 * q + 2] = b.z; v[16 + 4 * q + 3] = b.w;
    }
    float lg[NC];
    #pragma unroll
    for (int ct = 0; ct < 10; ++ct) {
        float ax = sb2[ct * 4 + 0], ay = sb2[ct * 4 + 1], az = sb2[ct * 4 + 2], aw = sb2[ct * 4 + 3];
        #pragma unroll
        for (int f = 0; f < 32; ++f) {
            float4 wv = w4[f][ct];
            ax += v[f] * wv.x; ay += v[f] * wv.y; az += v[f] * wv.z; aw += v[f] * wv.w;
        }
        lg[ct * 4 + 0] = ax; lg[ct * 4 + 1] = ay; lg[ct * 4 + 2] = az; lg[ct * 4 + 3] = aw;
    }
    float m = lg[0];
    #pragma unroll
    for (int c = 1; c < NC; ++c) m = fmaxf(m, lg[c]);
    float sum = 0.f;
    #pragma unroll
    for (int c = 0; c < NC; ++c) sum += __expf(lg[c] - m);
    float lse = m + __logf(sum);
    float* orow = out + node * NC;
    #pragma unroll
    for (int ct = 0; ct < 10; ++ct) {
        float4 r;
        r.x = lg[ct * 4 + 0] - lse; r.y = lg[ct * 4 + 1] - lse;
        r.z = lg[ct * 4 + 2] - lse; r.w = lg[ct * 4 + 3] - lse;
        *(float4*)(orow + ct * 4) = r;
    }
}

extern "C" void kernel_launch(void* const* d_in, const int* in_sizes, int n_in,
                              void* d_out, int out_size, void* d_ws, size_t ws_size,
                              hipStream_t stream) {
    const float* x  = (const float*)d_in[0];
    const float* ew = (const float*)d_in[1];
    const float* W1 = (const float*)d_in[2];
    const float* b1 = (const float*)d_in[3];
    const float* W2 = (const float*)d_in[4];
    const float* b2 = (const float*)d_in[5];
    const int*   ei = (const int*)d_in[6];
    const int* src = ei;
    const int* dst = ei + NE;
    float* out = (float*)d_out;

    const int NPAD = 100352;
    int*   bcur    = (int*)d_ws;                       // 1024 i (64 padded cursors)
    u64*   stg     = (u64*)(bcur + 1024);              // NG*GCAP u64 (~13.3MB)
    u32*   edges4  = (u32*)(stg + (size_t)NG * GCAP);  // NE u32 (6.4MB)
    int*   row_ptr = (int*)(edges4 + NE);              // NPAD i (uses NN+1)
    float* dinv    = (float*)(row_ptr + NPAD);         // NPAD f
    float* A1      = dinv + NPAD;                      // NN*HID f
    float* B0p     = A1 + NN * HID;                    // NN*HID f
    float* h       = B0p + NN * HID;                   // NN*HID f
    float* h2      = h + NN * HID;                     // NN*HID f
    float* Th      = h2 + NN * HID;                    // NN*HID f

    hipMemsetAsync(bcur, 0, 1024 * sizeof(int), stream);

    k_bucket<<<(NE + 1023) / 1024, 256, 0, stream>>>(src, dst, ew, bcur, stg);
    k_build<<<NG, 256, 0, stream>>>(stg, bcur, row_ptr, dinv, edges4);
    k_mm1<<<(NN + 7) / 8, 256, 0, stream>>>(x, W1, dinv, A1, B0p);
    k_gather<0><<<(NN + 3) / 4, 256, 0, stream>>>(row_ptr, edges4, B0p, A1, b1, dinv, h, h2);
    k_gather<1><<<(NN + 3) / 4, 256, 0, stream>>>(row_ptr, edges4, h2, nullptr, nullptr, dinv, Th, nullptr);
    k_mm2_lsm<<<(NN + 255) / 256, 256, 0, stream>>>(h, Th, W2, b2, out);
}

// Round 9
// 188.527 us; speedup vs baseline: 4.2452x; 1.1303x over previous
//
#include <hip/hip_runtime.h>
#include <math.h>

#define NN 100000
#define NE 1600000
#define FIN 64
#define HID 16
#define NC 40

#define NG 64       // dst-range groups (buckets)
#define GN 1563     // nodes per group: 64*1563 = 100032 >= NN
#define GCAP 26000  // staging capacity per bucket (expect ~25000, +6 sigma safe)
#define CHB 7       // scan chunk per thread: 7*256 = 1792 >= GN

typedef unsigned int u32;
typedef unsigned long long u64;
typedef unsigned short u16;

__device__ inline u16 f2bf(float f) {
    u32 u = __float_as_uint(f);
    return (u16)((u + 0x7FFF + ((u >> 16) & 1)) >> 16);  // RNE
}
__device__ inline float bf2f(u16 v) { return __uint_as_float(((u32)v) << 16); }

// ---- phase 1: bucket scatter (no per-edge global atomics) ----
// staging record: hi32 = local_d, lo32 = s | (ewq15 << 17)
__global__ void k_bucket(const int* __restrict__ src, const int* __restrict__ dst,
                         const float* __restrict__ ew,
                         int* __restrict__ bcur,  // 64 cursors padded 16-stride
                         u64* __restrict__ stg) {
    __shared__ int lcnt[NG];
    __shared__ int lpos[NG];
    int tid = threadIdx.x;
    if (tid < NG) lcnt[tid] = 0;
    __syncthreads();
    int g[4];
    u64 rec[4];
    int e0 = blockIdx.x * 1024 + tid;
    #pragma unroll
    for (int k = 0; k < 4; ++k) {
        int e = e0 + k * 256;
        g[k] = -1;
        if (e < NE) {
            int d = dst[e];
            int s = src[e];
            u32 q = (u32)fminf(ew[e] * 32767.f + 0.5f, 32767.f);
            int gg = d / GN;
            g[k] = gg;
            rec[k] = ((u64)(d - gg * GN) << 32) | (u64)(u32)(s | (q << 17));
            atomicAdd(&lcnt[gg], 1);
        }
    }
    __syncthreads();
    if (tid < NG) lpos[tid] = atomicAdd(&bcur[tid << 4], lcnt[tid]);
    __syncthreads();
    #pragma unroll
    for (int k = 0; k < 4; ++k) {
        if (g[k] >= 0) {
            int slot = atomicAdd(&lpos[g[k]], 1);
            if (slot < GCAP) stg[(size_t)g[k] * GCAP + slot] = rec[k];
        }
    }
}

// ---- fused builder: hist + scan + row_ptr/dinv + placement, one block per group ----
__global__ void __launch_bounds__(256) k_build(const u64* __restrict__ stg,
                                               const int* __restrict__ bcur,
                                               int* __restrict__ row_ptr,
                                               float* __restrict__ dinv,
                                               u32* __restrict__ edges4) {
    __shared__ u32 hc[GN];   // counts, then reused as cursors
    __shared__ u32 hw[GN];   // fixed-point weighted degree
    __shared__ int tsum[256];
    __shared__ int sbc[NG];
    __shared__ int gbase;
    int g = blockIdx.x, tid = threadIdx.x;
    for (int i = tid; i < GN; i += 256) { hc[i] = 0; hw[i] = 0; }
    if (tid < NG) sbc[tid] = bcur[tid << 4];
    __syncthreads();
    int n = sbc[g];
    const u64* base = stg + (size_t)g * GCAP;
    int i = tid;
    for (; i + 768 < n; i += 1024) {
        u64 r0 = base[i], r1 = base[i + 256], r2 = base[i + 512], r3 = base[i + 768];
        atomicAdd(&hc[(int)(r0 >> 32)], 1u); atomicAdd(&hw[(int)(r0 >> 32)], ((u32)r0) >> 17);
        atomicAdd(&hc[(int)(r1 >> 32)], 1u); atomicAdd(&hw[(int)(r1 >> 32)], ((u32)r1) >> 17);
        atomicAdd(&hc[(int)(r2 >> 32)], 1u); atomicAdd(&hw[(int)(r2 >> 32)], ((u32)r2) >> 17);
        atomicAdd(&hc[(int)(r3 >> 32)], 1u); atomicAdd(&hw[(int)(r3 >> 32)], ((u32)r3) >> 17);
    }
    for (; i < n; i += 256) {
        u64 r = base[i];
        atomicAdd(&hc[(int)(r >> 32)], 1u); atomicAdd(&hw[(int)(r >> 32)], ((u32)r) >> 17);
    }
    __syncthreads();
    if (tid == 0) {
        int off = 0;
        for (int q = 0; q < g; ++q) off += sbc[q];
        gbase = off;
    }
    int k0 = tid * CHB;
    u32 loc[CHB];
    int s = 0;
    #pragma unroll
    for (int q = 0; q < CHB; ++q) {
        int k = k0 + q;
        loc[q] = (k < GN) ? hc[k] : 0;
        s += (int)loc[q];
    }
    tsum[tid] = s;
    __syncthreads();
    #pragma unroll
    for (int off = 1; off < 256; off <<= 1) {
        int t = tid >= off ? tsum[tid - off] : 0;
        __syncthreads();
        tsum[tid] += t;
        __syncthreads();
    }
    int run = gbase + tsum[tid] - s;
    int n0 = g * GN;
    #pragma unroll
    for (int q = 0; q < CHB; ++q) {
        int k = k0 + q;
        if (k < GN) {
            int nd = n0 + k;
            if (nd <= NN) row_ptr[nd] = run;
            if (nd < NN) {
                float deg = (float)hw[k] * (1.0f / 32767.0f);
                dinv[nd] = deg > 0.f ? rsqrtf(fmaxf(deg, 1e-30f)) : 0.f;
            }
            hc[k] = (u32)run;
            run += (int)loc[q];
        }
    }
    __syncthreads();
    i = tid;
    for (; i + 768 < n; i += 1024) {
        u64 r0 = base[i], r1 = base[i + 256], r2 = base[i + 512], r3 = base[i + 768];
        edges4[atomicAdd(&hc[(int)(r0 >> 32)], 1u)] = (u32)r0;
        edges4[atomicAdd(&hc[(int)(r1 >> 32)], 1u)] = (u32)r1;
        edges4[atomicAdd(&hc[(int)(r2 >> 32)], 1u)] = (u32)r2;
        edges4[atomicAdd(&hc[(int)(r3 >> 32)], 1u)] = (u32)r3;
    }
    for (; i < n; i += 256) {
        u64 r = base[i];
        edges4[atomicAdd(&hc[(int)(r >> 32)], 1u)] = (u32)r;
    }
}

// ---- mm1: 2 threads per node. sel0 -> A1 row (f32), sel1 -> B0p row (bf16, *dinv) ----
__global__ void __launch_bounds__(256) k_mm1(const float* __restrict__ x,
                                             const float* __restrict__ W1,
                                             const float* __restrict__ dinv,
                                             float* __restrict__ A1,
                                             u16* __restrict__ B0h) {
    __shared__ float4 w4[512];  // [sel*256 + f*4 + jt] = W1 flat [2][64][16]
    int tid = threadIdx.x;
    for (int i = tid; i < 512; i += 256) w4[i] = *(const float4*)(W1 + i * 4);
    __syncthreads();
    int sel = tid >> 7;                       // wave-uniform
    int node = blockIdx.x * 128 + (tid & 127);
    if (node >= NN) return;
    const float4* xr = (const float4*)(x + node * FIN);
    const float4* wb = w4 + sel * 256;
    float4 a0 = {0,0,0,0}, a1 = {0,0,0,0}, a2 = {0,0,0,0}, a3 = {0,0,0,0};
    #pragma unroll
    for (int ft = 0; ft < 16; ++ft) {
        float4 xv = xr[ft];
        const float4* wf = wb + ft * 16;
        #pragma unroll
        for (int q = 0; q < 4; ++q) {
            float xs = q == 0 ? xv.x : q == 1 ? xv.y : q == 2 ? xv.z : xv.w;
            float4 w0 = wf[q * 4 + 0], w1v = wf[q * 4 + 1], w2v = wf[q * 4 + 2], w3v = wf[q * 4 + 3];
            a0.x += xs * w0.x; a0.y += xs * w0.y; a0.z += xs * w0.z; a0.w += xs * w0.w;
            a1.x += xs * w1v.x; a1.y += xs * w1v.y; a1.z += xs * w1v.z; a1.w += xs * w1v.w;
            a2.x += xs * w2v.x; a2.y += xs * w2v.y; a2.z += xs * w2v.z; a2.w += xs * w2v.w;
            a3.x += xs * w3v.x; a3.y += xs * w3v.y; a3.z += xs * w3v.z; a3.w += xs * w3v.w;
        }
    }
    if (sel == 0) {
        float4* o = (float4*)(A1 + node * HID);
        o[0] = a0; o[1] = a1; o[2] = a2; o[3] = a3;
    } else {
        float di = dinv[node];
        uint4 p0, p1;
        p0.x = f2bf(a0.x * di) | ((u32)f2bf(a0.y * di) << 16);
        p0.y = f2bf(a0.z * di) | ((u32)f2bf(a0.w * di) << 16);
        p0.z = f2bf(a1.x * di) | ((u32)f2bf(a1.y * di) << 16);
        p0.w = f2bf(a1.z * di) | ((u32)f2bf(a1.w * di) << 16);
        p1.x = f2bf(a2.x * di) | ((u32)f2bf(a2.y * di) << 16);
        p1.y = f2bf(a2.z * di) | ((u32)f2bf(a2.w * di) << 16);
        p1.z = f2bf(a3.x * di) | ((u32)f2bf(a3.y * di) << 16);
        p1.w = f2bf(a3.z * di) | ((u32)f2bf(a3.w * di) << 16);
        uint4* o = (uint4*)(B0h + node * HID);
        o[0] = p0; o[1] = p1;
    }
}

// wave per node, 4 edge-slots x 16 feats, bf16 B rows (L2-resident 3.2MB).
// MODE 0: h = relu(A1 - dinv*acc + b1) -> o1 f32; o2 = bf16(h*dinv)
// MODE 1: Th = -dinv*acc -> o1 f32
template <int MODE>
__global__ void k_gather(const int* __restrict__ row_ptr, const u32* __restrict__ edges4,
                         const u16* __restrict__ Bh,
                         const float* __restrict__ A1, const float* __restrict__ b1,
                         const float* __restrict__ dinv,
                         float* __restrict__ o1, u16* __restrict__ o2) {
    int node = blockIdx.x * 4 + (threadIdx.x >> 6);
    int lane = threadIdx.x & 63;
    int es = lane >> 4, j = lane & 15;
    if (node >= NN) return;
    int beg = row_ptr[node], end = row_ptr[node + 1];
    float a0 = 0.f, a1v = 0.f, a2 = 0.f, a3 = 0.f;
    int p = beg + es;
    for (; p + 12 < end; p += 16) {
        u32 r0 = edges4[p];
        u32 r1 = edges4[p + 4];
        u32 r2 = edges4[p + 8];
        u32 r3 = edges4[p + 12];
        a0  += (float)(r0 >> 17) * bf2f(Bh[(r0 & 0x1FFFF) * HID + j]);
        a1v += (float)(r1 >> 17) * bf2f(Bh[(r1 & 0x1FFFF) * HID + j]);
        a2  += (float)(r2 >> 17) * bf2f(Bh[(r2 & 0x1FFFF) * HID + j]);
        a3  += (float)(r3 >> 17) * bf2f(Bh[(r3 & 0x1FFFF) * HID + j]);
    }
    for (; p < end; p += 4) {
        u32 r = edges4[p];
        a0 += (float)(r >> 17) * bf2f(Bh[(r & 0x1FFFF) * HID + j]);
    }
    float acc = ((a0 + a1v) + (a2 + a3)) * (1.0f / 32767.0f);
    acc += __shfl_xor(acc, 16, 64);
    acc += __shfl_xor(acc, 32, 64);
    if (es == 0) {
        float di = dinv[node];
        if (MODE == 0) {
            float v = A1[node * HID + j] - di * acc + b1[j];
            float hh = fmaxf(v, 0.f);
            o1[node * HID + j] = hh;
            o2[node * HID + j] = f2bf(hh * di);
        } else {
            o1[node * HID + j] = -di * acc;
        }
    }
}

// thread-per-node: logits in regs, W2 broadcast from LDS, native exp/log
__global__ void __launch_bounds__(256) k_mm2_lsm(const float* __restrict__ h,
                                                 const float* __restrict__ Th,
                                                 const float* __restrict__ W2,
                                                 const float* __restrict__ b2,
                                                 float* __restrict__ out) {
    __shared__ float4 w4[32][10];
    __shared__ float sb2[NC];
    int tid = threadIdx.x;
    for (int i = tid; i < 320; i += 256) {
        int f = i / 10, ct = i % 10;
        w4[f][ct] = *(const float4*)(W2 + f * 40 + ct * 4);
    }
    for (int i = tid; i < NC; i += 256) sb2[i] = b2[i];
    __syncthreads();
    int node = blockIdx.x * 256 + tid;
    if (node >= NN) return;
    float v[32];
    const float4* hp = (const float4*)(h + node * HID);
    const float4* tp = (const float4*)(Th + node * HID);
    #pragma unroll
    for (int q = 0; q < 4; ++q) {
        float4 a = hp[q];
        v[4 * q + 0] = a.x; v[4 * q + 1] = a.y; v[4 * q + 2] = a.z; v[4 * q + 3] = a.w;
        float4 b = tp[q];
        v[16 + 4 * q + 0] = b.x; v[16 + 4 * q + 1] = b.y; v[16 + 4 * q + 2] = b.z; v[16 + 4 * q + 3] = b.w;
    }
    float lg[NC];
    #pragma unroll
    for (int ct = 0; ct < 10; ++ct) {
        float ax = sb2[ct * 4 + 0], ay = sb2[ct * 4 + 1], az = sb2[ct * 4 + 2], aw = sb2[ct * 4 + 3];
        #pragma unroll
        for (int f = 0; f < 32; ++f) {
            float4 wv = w4[f][ct];
            ax += v[f] * wv.x; ay += v[f] * wv.y; az += v[f] * wv.z; aw += v[f] * wv.w;
        }
        lg[ct * 4 + 0] = ax; lg[ct * 4 + 1] = ay; lg[ct * 4 + 2] = az; lg[ct * 4 + 3] = aw;
    }
    float m = lg[0];
    #pragma unroll
    for (int c = 1; c < NC; ++c) m = fmaxf(m, lg[c]);
    float sum = 0.f;
    #pragma unroll
    for (int c = 0; c < NC; ++c) sum += __expf(lg[c] - m);
    float lse = m + __logf(sum);
    float* orow = out + node * NC;
    #pragma unroll
    for (int ct = 0; ct < 10; ++ct) {
        float4 r;
        r.x = lg[ct * 4 + 0] - lse; r.y = lg[ct * 4 + 1] - lse;
        r.z = lg[ct * 4 + 2] - lse; r.w = lg[ct * 4 + 3] - lse;
        *(float4*)(orow + ct * 4) = r;
    }
}

extern "C" void kernel_launch(void* const* d_in, const int* in_sizes, int n_in,
                              void* d_out, int out_size, void* d_ws, size_t ws_size,
                              hipStream_t stream) {
    const float* x  = (const float*)d_in[0];
    const float* ew = (const float*)d_in[1];
    const float* W1 = (const float*)d_in[2];
    const float* b1 = (const float*)d_in[3];
    const float* W2 = (const float*)d_in[4];
    const float* b2 = (const float*)d_in[5];
    const int*   ei = (const int*)d_in[6];
    const int* src = ei;
    const int* dst = ei + NE;
    float* out = (float*)d_out;

    const int NPAD = 100352;
    int*   bcur    = (int*)d_ws;                       // 1024 i
    u64*   stg     = (u64*)(bcur + 1024);              // NG*GCAP u64 (~13.3MB)
    u32*   edges4  = (u32*)(stg + (size_t)NG * GCAP);  // NE u32 (6.4MB)
    int*   row_ptr = (int*)(edges4 + NE);              // NPAD i (uses NN+1)
    float* dinv    = (float*)(row_ptr + NPAD);         // NPAD f
    float* A1      = dinv + NPAD;                      // NN*HID f
    float* h       = A1 + NN * HID;                    // NN*HID f
    float* Th      = h + NN * HID;                     // NN*HID f
    u16*   B0h     = (u16*)(Th + NN * HID);            // NN*HID u16 (3.2MB)
    u16*   h2      = B0h + NN * HID;                   // NN*HID u16 (3.2MB)

    hipMemsetAsync(bcur, 0, 1024 * sizeof(int), stream);

    k_bucket<<<(NE + 1023) / 1024, 256, 0, stream>>>(src, dst, ew, bcur, stg);
    k_build<<<NG, 256, 0, stream>>>(stg, bcur, row_ptr, dinv, edges4);
    k_mm1<<<(NN + 127) / 128, 256, 0, stream>>>(x, W1, dinv, A1, B0h);
    k_gather<0><<<(NN + 3) / 4, 256, 0, stream>>>(row_ptr, edges4, B0h, A1, b1, dinv, h, h2);
    k_gather<1><<<(NN + 3) / 4, 256, 0, stream>>>(row_ptr, edges4, h2, nullptr, nullptr, dinv, Th, nullptr);
    k_mm2_lsm<<<(NN + 255) / 256, 256, 0, stream>>>(h, Th, W2, b2, out);
}